// Round 16
// baseline (1737.556 us; speedup 1.0000x reference)
//
#include <hip/hip_runtime.h>
#include <math.h>

#define TPB 256
#define WPB 4

// per-wave LDS floats: KV[48][38] (K bf16 36 | V bf16 36 | 2 pad) + SZ bf16[48][36]
// KV row ushorts: K = c (0..35), V = 36+c (36..71), pad 72..75
constexpr int WAVE_F = 2688;          // 1824 + 864 ; block = 4*2688*4 = 43008 B -> 3 blocks/CU
constexpr int O_SZ   = 1824;

// d_ws weight-table offsets (floats)
constexpr int OW_UP  = 0;       // [6][72][18] up-proj transposed
constexpr int OW_AB  = 7776;    // [6][4][2][36] gate fold
constexpr int OW_FUP = 9504;    // [128][18] FFN up transposed

__device__ __forceinline__ float sigm(float v){ return 1.f/(1.f+__expf(-v)); }
__device__ __forceinline__ float siluf(float v){ return v/(1.f+__expf(-v)); }
__device__ __forceinline__ float logsig(float v){ return fminf(v,0.f) - log1pf(__expf(-fabsf(v))); }
__device__ __forceinline__ float sqf(float v){ return v*v; }
__device__ __forceinline__ unsigned short f2b(float v){
  union{float f; unsigned u;} c; c.f=v; unsigned u=c.u;
  return (unsigned short)((u + 0x7FFFu + ((u>>16)&1u))>>16);
}
__device__ __forceinline__ float b2f(unsigned short s){
  union{unsigned u; float f;} c; c.u=((unsigned)s)<<16; return c.f;
}
__device__ __forceinline__ float u2f(unsigned u){
  union{unsigned u; float f;} c; c.u=u; return c.f;
}
__device__ __forceinline__ unsigned packbf(float a, float b){
  return (unsigned)f2b(a) | ((unsigned)f2b(b)<<16);
}

struct V18 { float4 a,b,c,d; float2 e; };
struct V36 { float4 g0,g1,g2,g3,g4,g5,g6,g7,g8; };

template<int I> __device__ __forceinline__ float elc(const V18& v){
  if constexpr(I==0) return v.a.x; else if constexpr(I==1) return v.a.y;
  else if constexpr(I==2) return v.a.z; else if constexpr(I==3) return v.a.w;
  else if constexpr(I==4) return v.b.x; else if constexpr(I==5) return v.b.y;
  else if constexpr(I==6) return v.b.z; else if constexpr(I==7) return v.b.w;
  else if constexpr(I==8) return v.c.x; else if constexpr(I==9) return v.c.y;
  else if constexpr(I==10) return v.c.z; else if constexpr(I==11) return v.c.w;
  else if constexpr(I==12) return v.d.x; else if constexpr(I==13) return v.d.y;
  else if constexpr(I==14) return v.d.z; else if constexpr(I==15) return v.d.w;
  else if constexpr(I==16) return v.e.x; else return v.e.y;
}
template<int I> __device__ __forceinline__ void setv(V18& v, float x){
  if constexpr(I==0) v.a.x=x; else if constexpr(I==1) v.a.y=x;
  else if constexpr(I==2) v.a.z=x; else if constexpr(I==3) v.a.w=x;
  else if constexpr(I==4) v.b.x=x; else if constexpr(I==5) v.b.y=x;
  else if constexpr(I==6) v.b.z=x; else if constexpr(I==7) v.b.w=x;
  else if constexpr(I==8) v.c.x=x; else if constexpr(I==9) v.c.y=x;
  else if constexpr(I==10) v.c.z=x; else if constexpr(I==11) v.c.w=x;
  else if constexpr(I==12) v.d.x=x; else if constexpr(I==13) v.d.y=x;
  else if constexpr(I==14) v.d.z=x; else if constexpr(I==15) v.d.w=x;
  else if constexpr(I==16) v.e.x=x; else v.e.y=x;
}
template<int G> __device__ __forceinline__ float4& grp(V36& q){
  if constexpr(G==0) return q.g0; else if constexpr(G==1) return q.g1;
  else if constexpr(G==2) return q.g2; else if constexpr(G==3) return q.g3;
  else if constexpr(G==4) return q.g4; else if constexpr(G==5) return q.g5;
  else if constexpr(G==6) return q.g6; else if constexpr(G==7) return q.g7;
  else return q.g8;
}

__device__ __forceinline__ float dot18(const V18& h, const float* __restrict__ w){
  return h.a.x*w[0]+h.a.y*w[1]+h.a.z*w[2]+h.a.w*w[3]
       + h.b.x*w[4]+h.b.y*w[5]+h.b.z*w[6]+h.b.w*w[7]
       + h.c.x*w[8]+h.c.y*w[9]+h.c.z*w[10]+h.c.w*w[11]
       + h.d.x*w[12]+h.d.y*w[13]+h.d.z*w[14]+h.d.w*w[15]
       + h.e.x*w[16]+h.e.y*w[17];
}
__device__ __forceinline__ void axpy18(V18& x, float s, const float* __restrict__ w){
  x.a.x+=s*w[0];  x.a.y+=s*w[1];  x.a.z+=s*w[2];  x.a.w+=s*w[3];
  x.b.x+=s*w[4];  x.b.y+=s*w[5];  x.b.z+=s*w[6];  x.b.w+=s*w[7];
  x.c.x+=s*w[8];  x.c.y+=s*w[9];  x.c.z+=s*w[10]; x.c.w+=s*w[11];
  x.d.x+=s*w[12]; x.d.y+=s*w[13]; x.d.z+=s*w[14]; x.d.w+=s*w[15];
  x.e.x+=s*w[16]; x.e.y+=s*w[17];
}

#define L18(M) M(0) M(1) M(2) M(3) M(4) M(5) M(6) M(7) M(8) M(9) M(10) M(11) M(12) M(13) M(14) M(15) M(16) M(17)
#define L9(M) M(0) M(1) M(2) M(3) M(4) M(5) M(6) M(7) M(8)

extern "C" __global__ void prep_kernel(
    const float* __restrict__ up,  const float* __restrict__ qw, const float* __restrict__ kw,
    const float* __restrict__ vw,  const float* __restrict__ igw,const float* __restrict__ fgw,
    const float* __restrict__ fup, float* __restrict__ W)
{
  const int tid = threadIdx.x;
  for (int i=tid;i<7776;i+=256){ int mj=i/1296, r=i%1296, o=r/18, d=r%18; W[OW_UP+i]=up[mj*1296+d*72+o]; }
  for (int i=tid;i<1728;i+=256){
    int mj=i/288, r=i%288, gh=r/72, w2=(r%72)/36, c=r%36;
    int g=gh>>1,h=gh&1,n=c>>2,d=c&3;
    const float* gwp=(g? fgw:igw)+mj*216+h*108;
    float val=0.f;
    if(w2==0){ for(int o=0;o<4;++o) val += qw[mj*144+n*16+o*4+d]*gwp[n*4+o] + kw[mj*144+n*16+o*4+d]*gwp[36+n*4+o]; }
    else     { for(int o=0;o<4;++o) val += vw[mj*144+n*16+o*4+d]*gwp[72+n*4+o]; }
    W[OW_AB+i]=val;
  }
  for (int i=tid;i<2304;i+=256){ int f=i/18, d=i%18; W[OW_FUP+i]=fup[d*128+f]; }
}

template<int G>
__device__ __forceinline__ void proj_g(const V18& h, V18& x, V36& q,
    float* kvrow, unsigned short* szrow, int lane,
    const float* __restrict__ wup, const float* __restrict__ wab,
    const float* __restrict__ cw,  const float* __restrict__ cb,
    const float* __restrict__ qw,  const float* __restrict__ kw, const float* __restrict__ vw,
    const float* __restrict__ skp, const float* __restrict__ dwn,
    float& gi0, float& gi1, float& gf0, float& gf1)
{
  constexpr int C0=4*G;
  float m0=dot18(h,wup+(C0+0)*18), m1=dot18(h,wup+(C0+1)*18),
        m2=dot18(h,wup+(C0+2)*18), m3=dot18(h,wup+(C0+3)*18);
  if(lane>=48){ m0=0.f;m1=0.f;m2=0.f;m3=0.f; }
  float c0,c1,c2,c3;
  { float p1=__shfl(m0,lane-1),p2=__shfl(m0,lane-2),p3=__shfl(m0,lane-3);
    c0=siluf(cb[C0+0]+p3*cw[(C0+0)*4]+p2*cw[(C0+0)*4+1]+p1*cw[(C0+0)*4+2]+m0*cw[(C0+0)*4+3]); }
  { float p1=__shfl(m1,lane-1),p2=__shfl(m1,lane-2),p3=__shfl(m1,lane-3);
    c1=siluf(cb[C0+1]+p3*cw[(C0+1)*4]+p2*cw[(C0+1)*4+1]+p1*cw[(C0+1)*4+2]+m1*cw[(C0+1)*4+3]); }
  { float p1=__shfl(m2,lane-1),p2=__shfl(m2,lane-2),p3=__shfl(m2,lane-3);
    c2=siluf(cb[C0+2]+p3*cw[(C0+2)*4]+p2*cw[(C0+2)*4+1]+p1*cw[(C0+2)*4+2]+m2*cw[(C0+2)*4+3]); }
  { float p1=__shfl(m3,lane-1),p2=__shfl(m3,lane-2),p3=__shfl(m3,lane-3);
    c3=siluf(cb[C0+3]+p3*cw[(C0+3)*4]+p2*cw[(C0+3)*4+1]+p1*cw[(C0+3)*4+2]+m3*cw[(C0+3)*4+3]); }
  const float s0=siluf(dot18(h,wup+(36+C0+0)*18));
  const float s1=siluf(dot18(h,wup+(36+C0+1)*18));
  const float s2=siluf(dot18(h,wup+(36+C0+2)*18));
  const float s3=siluf(dot18(h,wup+(36+C0+3)*18));
  gi0 += c0*wab[C0+0]+c1*wab[C0+1]+c2*wab[C0+2]+c3*wab[C0+3]
       + m0*wab[36+C0+0]+m1*wab[36+C0+1]+m2*wab[36+C0+2]+m3*wab[36+C0+3];
  gi1 += c0*wab[72+C0+0]+c1*wab[72+C0+1]+c2*wab[72+C0+2]+c3*wab[72+C0+3]
       + m0*wab[108+C0+0]+m1*wab[108+C0+1]+m2*wab[108+C0+2]+m3*wab[108+C0+3];
  gf0 += c0*wab[144+C0+0]+c1*wab[144+C0+1]+c2*wab[144+C0+2]+c3*wab[144+C0+3]
       + m0*wab[180+C0+0]+m1*wab[180+C0+1]+m2*wab[180+C0+2]+m3*wab[180+C0+3];
  gf1 += c0*wab[216+C0+0]+c1*wab[216+C0+1]+c2*wab[216+C0+2]+c3*wab[216+C0+3]
       + m0*wab[252+C0+0]+m1*wab[252+C0+1]+m2*wab[252+C0+2]+m3*wab[252+C0+3];
  if(lane<48){
    uint2 ss; ss.x=packbf(s0,s1); ss.y=packbf(s2,s3);
    *reinterpret_cast<uint2*>(reinterpret_cast<unsigned*>(szrow) + (C0>>1)) = ss;
    const float kt0=c0*kw[G*16+0] +c1*kw[G*16+1] +c2*kw[G*16+2] +c3*kw[G*16+3];
    const float kt1=c0*kw[G*16+4] +c1*kw[G*16+5] +c2*kw[G*16+6] +c3*kw[G*16+7];
    const float kt2=c0*kw[G*16+8] +c1*kw[G*16+9] +c2*kw[G*16+10]+c3*kw[G*16+11];
    const float kt3=c0*kw[G*16+12]+c1*kw[G*16+13]+c2*kw[G*16+14]+c3*kw[G*16+15];
    const float vt0=m0*vw[G*16+0] +m1*vw[G*16+1] +m2*vw[G*16+2] +m3*vw[G*16+3];
    const float vt1=m0*vw[G*16+4] +m1*vw[G*16+5] +m2*vw[G*16+6] +m3*vw[G*16+7];
    const float vt2=m0*vw[G*16+8] +m1*vw[G*16+9] +m2*vw[G*16+10]+m3*vw[G*16+11];
    const float vt3=m0*vw[G*16+12]+m1*vw[G*16+13]+m2*vw[G*16+14]+m3*vw[G*16+15];
    unsigned* urow = reinterpret_cast<unsigned*>(kvrow);
    uint2 kk2; kk2.x=packbf(kt0,kt1); kk2.y=packbf(kt2,kt3);
    *reinterpret_cast<uint2*>(urow + 2*G) = kk2;
    uint2 vv2; vv2.x=packbf(vt0,vt1); vv2.y=packbf(vt2,vt3);
    *reinterpret_cast<uint2*>(urow + 18 + 2*G) = vv2;
  }
  float4 qt;
  qt.x=c0*qw[G*16+0] +c1*qw[G*16+1] +c2*qw[G*16+2] +c3*qw[G*16+3];
  qt.y=c0*qw[G*16+4] +c1*qw[G*16+5] +c2*qw[G*16+6] +c3*qw[G*16+7];
  qt.z=c0*qw[G*16+8] +c1*qw[G*16+9] +c2*qw[G*16+10]+c3*qw[G*16+11];
  qt.w=c0*qw[G*16+12]+c1*qw[G*16+13]+c2*qw[G*16+14]+c3*qw[G*16+15];
  grp<G>(q)=qt;
  axpy18(x, skp[C0+0]*c0*s0, dwn+(C0+0)*18);
  axpy18(x, skp[C0+1]*c1*s1, dwn+(C0+1)*18);
  axpy18(x, skp[C0+2]*c2*s2, dwn+(C0+2)*18);
  axpy18(x, skp[C0+3]*c3*s3, dwn+(C0+3)*18);
}

#define UNP(u, lo, hi) const float lo = u2f((u)<<16); const float hi = u2f((u)&0xffff0000u);

template<int HH>
__device__ __forceinline__ void attn_fold(const V36& q, V18& x, int lane,
    const float* KV, const unsigned short* szrow,
    float ipt, float lf, float u,
    const float* __restrict__ onw, const float* __restrict__ dwn)
{
  V18 acc;
  { float4 z4{0.f,0.f,0.f,0.f}; acc.a=z4; acc.b=z4; acc.c=z4; acc.d=z4; acc.e.x=0.f; acc.e.y=0.f; }
  float rs=0.f;
  const float rb=-u;
  const float scl=0.23570226039551584f;
  for(int t=0;t<48;++t){
    const float ipx = __shfl(ipt, t);
    const unsigned* ur = reinterpret_cast<const unsigned*>(KV + t*38);
    float qk;
    if constexpr(HH==0){
      const uint2 a0=*reinterpret_cast<const uint2*>(ur+0);
      const uint2 a1=*reinterpret_cast<const uint2*>(ur+2);
      const uint2 a2=*reinterpret_cast<const uint2*>(ur+4);
      const uint2 a3=*reinterpret_cast<const uint2*>(ur+6);
      const unsigned a4=ur[8];
      UNP(a0.x,k0,k1) UNP(a0.y,k2,k3) UNP(a1.x,k4,k5) UNP(a1.y,k6,k7)
      UNP(a2.x,k8,k9) UNP(a2.y,k10,k11) UNP(a3.x,k12,k13) UNP(a3.y,k14,k15)
      UNP(a4,k16,k17)
      qk = k0*q.g0.x+k1*q.g0.y+k2*q.g0.z+k3*q.g0.w
         + k4*q.g1.x+k5*q.g1.y+k6*q.g1.z+k7*q.g1.w
         + k8*q.g2.x+k9*q.g2.y+k10*q.g2.z+k11*q.g2.w
         + k12*q.g3.x+k13*q.g3.y+k14*q.g3.z+k15*q.g3.w
         + k16*q.g4.x+k17*q.g4.y;
    } else {
      const unsigned a0=ur[9];
      const uint2 a1=*reinterpret_cast<const uint2*>(ur+10);
      const uint2 a2=*reinterpret_cast<const uint2*>(ur+12);
      const uint2 a3=*reinterpret_cast<const uint2*>(ur+14);
      const uint2 a4=*reinterpret_cast<const uint2*>(ur+16);
      UNP(a0,k18,k19)
      UNP(a1.x,k20,k21) UNP(a1.y,k22,k23)
      UNP(a2.x,k24,k25) UNP(a2.y,k26,k27)
      UNP(a3.x,k28,k29) UNP(a3.y,k30,k31)
      UNP(a4.x,k32,k33) UNP(a4.y,k34,k35)
      qk = k18*q.g4.z+k19*q.g4.w
         + k20*q.g5.x+k21*q.g5.y+k22*q.g5.z+k23*q.g5.w
         + k24*q.g6.x+k25*q.g6.y+k26*q.g6.z+k27*q.g6.w
         + k28*q.g7.x+k29*q.g7.y+k30*q.g7.z+k31*q.g7.w
         + k32*q.g8.x+k33*q.g8.y+k34*q.g8.z+k35*q.g8.w;
    }
    const float e0=__expf(fminf(rb+ipx,0.f));
    const float cc = (t<=lane)? qk*scl*e0 : 0.f;
    rs+=cc;
    if constexpr(HH==0){
      const uint2 b0=*reinterpret_cast<const uint2*>(ur+18);
      const uint2 b1=*reinterpret_cast<const uint2*>(ur+20);
      const uint2 b2=*reinterpret_cast<const uint2*>(ur+22);
      const uint2 b3=*reinterpret_cast<const uint2*>(ur+24);
      const unsigned b4=ur[26];
      UNP(b0.x,v0,v1) UNP(b0.y,v2,v3) UNP(b1.x,v4,v5) UNP(b1.y,v6,v7)
      UNP(b2.x,v8,v9) UNP(b2.y,v10,v11) UNP(b3.x,v12,v13) UNP(b3.y,v14,v15)
      UNP(b4,v16,v17)
      acc.a.x+=cc*v0;  acc.a.y+=cc*v1;  acc.a.z+=cc*v2;  acc.a.w+=cc*v3;
      acc.b.x+=cc*v4;  acc.b.y+=cc*v5;  acc.b.z+=cc*v6;  acc.b.w+=cc*v7;
      acc.c.x+=cc*v8;  acc.c.y+=cc*v9;  acc.c.z+=cc*v10; acc.c.w+=cc*v11;
      acc.d.x+=cc*v12; acc.d.y+=cc*v13; acc.d.z+=cc*v14; acc.d.w+=cc*v15;
      acc.e.x+=cc*v16; acc.e.y+=cc*v17;
    } else {
      const unsigned b0=ur[27];
      const uint2 b1=*reinterpret_cast<const uint2*>(ur+28);
      const uint2 b2=*reinterpret_cast<const uint2*>(ur+30);
      const uint2 b3=*reinterpret_cast<const uint2*>(ur+32);
      const uint2 b4=*reinterpret_cast<const uint2*>(ur+34);
      UNP(b0,v0,v1)
      UNP(b1.x,v2,v3) UNP(b1.y,v4,v5)
      UNP(b2.x,v6,v7) UNP(b2.y,v8,v9)
      UNP(b3.x,v10,v11) UNP(b3.y,v12,v13)
      UNP(b4.x,v14,v15) UNP(b4.y,v16,v17)
      acc.a.x+=cc*v0;  acc.a.y+=cc*v1;  acc.a.z+=cc*v2;  acc.a.w+=cc*v3;
      acc.b.x+=cc*v4;  acc.b.y+=cc*v5;  acc.b.z+=cc*v6;  acc.b.w+=cc*v7;
      acc.c.x+=cc*v8;  acc.c.y+=cc*v9;  acc.c.z+=cc*v10; acc.c.w+=cc*v11;
      acc.d.x+=cc*v12; acc.d.y+=cc*v13; acc.d.z+=cc*v14; acc.d.w+=cc*v15;
      acc.e.x+=cc*v16; acc.e.y+=cc*v17;
    }
  }
  const float mr = lf+u;
  const float ninv = 1.f/(fmaxf(fabsf(rs), __expf(-mr))+1e-6f);
  #define AS(I) + elc<I>(acc)
  const float mb = (0.f L18(AS))*(1.f/18.f);
  #undef AS
  #define AV(I) + sqf(elc<I>(acc)-mb)
  const float vb2 = 0.f L18(AV);
  #undef AV
  const float rn = rsqrtf(ninv*ninv*vb2*(1.f/18.f)+1e-5f);
  #define FD(I) { const float hn=(elc<I>(acc)-mb)*ninv*rn*onw[HH*18+I]; \
                  axpy18(x, hn*b2f(szrow[HH*18+I]), dwn+(HH*18+I)*18); }
  L18(FD)
  #undef FD
}

__device__ __forceinline__ void mlstm(V18& x, int lane, float* WV, unsigned short* SZB,
    const float* __restrict__ lnw, const float* __restrict__ wup, const float* __restrict__ wab,
    const float* __restrict__ cw,  const float* __restrict__ cb,
    const float* __restrict__ qw,  const float* __restrict__ kw,  const float* __restrict__ vw,
    const float* __restrict__ igb, const float* __restrict__ fgb, const float* __restrict__ skp,
    const float* __restrict__ onw, const float* __restrict__ dwn)
{
  #define MS(I) + elc<I>(x)
  const float mu = (0.f L18(MS))*(1.f/18.f);
  #undef MS
  #define MV(I) + sqf(elc<I>(x)-mu)
  const float var = (0.f L18(MV))*(1.f/18.f);
  #undef MV
  const float rr = rsqrtf(var+1e-5f);
  V18 h;
  #define MH(I) setv<I>(h,(elc<I>(x)-mu)*rr*lnw[I]);
  L18(MH)
  #undef MH

  V36 q;
  float gi0=igb[0], gi1=igb[1], gf0=fgb[0], gf1=fgb[1];
  float* kvrow = WV + lane*38;
  const int sr = (lane<48)? lane : 0;
  unsigned short* szrow = SZB + sr*36;
  proj_g<0>(h,x,q,kvrow,szrow,lane,wup,wab,cw,cb,qw,kw,vw,skp,dwn,gi0,gi1,gf0,gf1);
  proj_g<1>(h,x,q,kvrow,szrow,lane,wup,wab,cw,cb,qw,kw,vw,skp,dwn,gi0,gi1,gf0,gf1);
  proj_g<2>(h,x,q,kvrow,szrow,lane,wup,wab,cw,cb,qw,kw,vw,skp,dwn,gi0,gi1,gf0,gf1);
  proj_g<3>(h,x,q,kvrow,szrow,lane,wup,wab,cw,cb,qw,kw,vw,skp,dwn,gi0,gi1,gf0,gf1);
  proj_g<4>(h,x,q,kvrow,szrow,lane,wup,wab,cw,cb,qw,kw,vw,skp,dwn,gi0,gi1,gf0,gf1);
  proj_g<5>(h,x,q,kvrow,szrow,lane,wup,wab,cw,cb,qw,kw,vw,skp,dwn,gi0,gi1,gf0,gf1);
  proj_g<6>(h,x,q,kvrow,szrow,lane,wup,wab,cw,cb,qw,kw,vw,skp,dwn,gi0,gi1,gf0,gf1);
  proj_g<7>(h,x,q,kvrow,szrow,lane,wup,wab,cw,cb,qw,kw,vw,skp,dwn,gi0,gi1,gf0,gf1);
  proj_g<8>(h,x,q,kvrow,szrow,lane,wup,wab,cw,cb,qw,kw,vw,skp,dwn,gi0,gi1,gf0,gf1);

  float lf0=logsig(gf0), lf1=logsig(gf1);
  #pragma unroll
  for(int off=1; off<64; off<<=1){
    float t0=__shfl_up(lf0,off), t1=__shfl_up(lf1,off);
    if(lane>=off){ lf0+=t0; lf1+=t1; }
  }
  const float ipt0=gi0-lf0, ipt1=gi1-lf1;
  float u0=ipt0, u1=ipt1;
  #pragma unroll
  for(int off=1; off<64; off<<=1){
    float t0=__shfl_up(u0,off), t1=__shfl_up(u1,off);
    if(lane>=off){ u0=fmaxf(u0,t0); u1=fmaxf(u1,t1); }
  }
  asm volatile("s_waitcnt lgkmcnt(0)" ::: "memory");

  attn_fold<0>(q, x, lane, WV, szrow, ipt0, lf0, u0, onw, dwn);
  attn_fold<1>(q, x, lane, WV, szrow, ipt1, lf1, u1, onw, dwn);
}

// sLSTM scan for one head: wx computed on the fly via __shfl broadcasts of h/hc.
template<int HH>
__device__ __forceinline__ void scan_head(const V18& h, const V18& hc, int lane, float* Y,
    const float* __restrict__ gw, const float* __restrict__ gb, const float* __restrict__ rw)
{
  const int li = (lane<36)? lane : 0;
  const int g=li/9, e=li%9;
  const float* gwb = gw + ((g*2+HH)*9+e)*9;
  const float w0=gwb[0],w1=gwb[1],w2=gwb[2],w3=gwb[3],w4=gwb[4],
              w5=gwb[5],w6=gwb[6],w7=gwb[7],w8=gwb[8];
  const float bias = gb[(g*2+HH)*9+e];
  const float* rwb = rw + HH*324 + g*9 + e;
  const float r0=rwb[0], r1=rwb[36], r2=rwb[72], r3=rwb[108], r4=rwb[144],
              r5=rwb[180], r6=rwb[216], r7=rwb[252], r8=rwb[288];
  const bool usehc = (g<2);
  float yv=0.f,cv=0.f,nv=0.f,mv=0.f;
  for(int st=0; st<48; ++st){
    float raw = bias;
    #define BIN(D,W) { const float bh=__shfl(elc<9*HH+D>(h),st); \
                       const float bc=__shfl(elc<9*HH+D>(hc),st); \
                       raw += (usehc? bc : bh)*W; }
    BIN(0,w0) BIN(1,w1) BIN(2,w2) BIN(3,w3) BIN(4,w4) BIN(5,w5) BIN(6,w6) BIN(7,w7) BIN(8,w8)
    #undef BIN
    raw += __shfl(yv,0)*r0 + __shfl(yv,1)*r1 + __shfl(yv,2)*r2
         + __shfl(yv,3)*r3 + __shfl(yv,4)*r4 + __shfl(yv,5)*r5
         + __shfl(yv,6)*r6 + __shfl(yv,7)*r7 + __shfl(yv,8)*r8;
    const float i_=__shfl(raw,e), f_=__shfl(raw,9+e), z_=__shfl(raw,18+e), o_=__shfl(raw,27+e);
    const float lfm=mv+logsig(f_);
    const float mn=fmaxf(i_,lfm);
    const float ig=__expf(i_-mn), fg=__expf(lfm-mn);
    const float th=1.f-2.f/(__expf(2.f*z_)+1.f);
    cv=fg*cv+ig*th;
    nv=fg*nv+ig; mv=mn;
    yv=sigm(o_)*cv/nv;
    if(lane<9) Y[st*18 + HH*9 + lane] = yv;
  }
}

__device__ __forceinline__ void slstm(V18& x, int lane, float* Y,
    const float* __restrict__ lnw, const float* __restrict__ cw, const float* __restrict__ cb,
    const float* __restrict__ gw,  const float* __restrict__ rw, const float* __restrict__ gb,
    const float* __restrict__ gnw, const float* __restrict__ flnw,
    const float* __restrict__ wfup,const float* __restrict__ fdw)
{
  #define SS(I) + elc<I>(x)
  const float mu = (0.f L18(SS))*(1.f/18.f);
  #undef SS
  #define SV(I) + sqf(elc<I>(x)-mu)
  const float var = (0.f L18(SV))*(1.f/18.f);
  #undef SV
  const float rr = rsqrtf(var+1e-5f);
  V18 h;
  #define SH(I) setv<I>(h,(lane<48)?(elc<I>(x)-mu)*rr*lnw[I]:0.f);
  L18(SH)
  #undef SH
  V18 hc;
  #define SC(I) { const float hv=elc<I>(h); \
    const float p1=__shfl(hv,lane-1),p2=__shfl(hv,lane-2),p3=__shfl(hv,lane-3); \
    setv<I>(hc, siluf(cb[I]+p3*cw[(I)*4]+p2*cw[(I)*4+1]+p1*cw[(I)*4+2]+hv*cw[(I)*4+3])); }
  L18(SC)
  #undef SC

  scan_head<0>(h, hc, lane, Y, gw, gb, rw);
  scan_head<1>(h, hc, lane, Y, gw, gb, rw);
  asm volatile("s_waitcnt lgkmcnt(0)" ::: "memory");

  if(lane<48){
    {
      float m2=0.f;
      for(int e=0;e<9;++e) m2+=Y[lane*18+e];
      m2*=(1.f/9.f);
      float vv=0.f;
      for(int e=0;e<9;++e){ float t=Y[lane*18+e]-m2; vv+=t*t; }
      const float r2=rsqrtf(vv*(1.f/9.f)+1e-5f);
      #define GN0(E) setv<E>(x, elc<E>(x)+(Y[lane*18+E]-m2)*r2*gnw[E]);
      L9(GN0)
      #undef GN0
    }
    {
      float m2=0.f;
      for(int e=0;e<9;++e) m2+=Y[lane*18+9+e];
      m2*=(1.f/9.f);
      float vv=0.f;
      for(int e=0;e<9;++e){ float t=Y[lane*18+9+e]-m2; vv+=t*t; }
      const float r2=rsqrtf(vv*(1.f/9.f)+1e-5f);
      #define GN1(E) setv<(9+E)>(x, elc<(9+E)>(x)+(Y[lane*18+9+E]-m2)*r2*gnw[9+E]);
      L9(GN1)
      #undef GN1
    }
  }

  #define FS(I) + elc<I>(x)
  const float mu2 = (0.f L18(FS))*(1.f/18.f);
  #undef FS
  #define FV(I) + sqf(elc<I>(x)-mu2)
  const float var2 = (0.f L18(FV))*(1.f/18.f);
  #undef FV
  const float rr2 = rsqrtf(var2+1e-5f);
  V18 h2;
  #define FH(I) setv<I>(h2,(elc<I>(x)-mu2)*rr2*flnw[I]);
  L18(FH)
  #undef FH
  for(int f=0;f<64;++f){
    const float ug=dot18(h2, wfup+f*18);
    const float uu=dot18(h2, wfup+(64+f)*18);
    const float ge=0.5f*ug*(1.f+erff(ug*0.70710678118654752f));
    axpy18(x, ge*uu, fdw+f*18);
  }
}

extern "C" __global__ void __launch_bounds__(TPB)
xlstm_kernel(const float* __restrict__ gx,
             const float* __restrict__ m_ln_w,  const float* __restrict__ m_conv_w,
             const float* __restrict__ m_conv_b,const float* __restrict__ m_q_w,
             const float* __restrict__ m_k_w,   const float* __restrict__ m_v_w,
             const float* __restrict__ m_ig_b,  const float* __restrict__ m_fg_b,
             const float* __restrict__ m_skip,  const float* __restrict__ m_on_w,
             const float* __restrict__ m_down_w,
             const float* __restrict__ s_ln_w,  const float* __restrict__ s_conv_w,
             const float* __restrict__ s_conv_b,const float* __restrict__ s_gate_w,
             const float* __restrict__ s_rec_w, const float* __restrict__ s_bias,
             const float* __restrict__ s_gn_w,  const float* __restrict__ f_ln_w,
             const float* __restrict__ f_down_w,
             const float* __restrict__ post_ln_w, const float* __restrict__ dense_w,
             const float* __restrict__ dense_b, const float* __restrict__ W,
             float* __restrict__ gout, const int Btot)
{
  __shared__ float L[WPB*WAVE_F];
  const int lane = threadIdx.x & 63;
  const int wv   = threadIdx.x >> 6;
  const int b    = blockIdx.x*WPB + wv;
  if (b >= Btot) return;
  float* WV = L + wv*WAVE_F;
  unsigned short* SZB = reinterpret_cast<unsigned short*>(WV + O_SZ);

  V18 x;
  const float* gxb = gx + b*864 + lane*18;
  #define XL(I) setv<I>(x,(lane<48)? gxb[I] : 0.f);
  L18(XL)
  #undef XL

  int mj=0;
  #pragma unroll 1
  for(int blk=0; blk<7; ++blk){
    if (blk==1){
      slstm(x, lane, WV, s_ln_w, s_conv_w, s_conv_b, s_gate_w, s_rec_w, s_bias,
            s_gn_w, f_ln_w, W+OW_FUP, f_down_w);
    } else {
      mlstm(x, lane, WV, SZB,
            m_ln_w+mj*18, W+OW_UP+mj*1296, W+OW_AB+mj*288,
            m_conv_w+mj*144, m_conv_b+mj*36,
            m_q_w+mj*144, m_k_w+mj*144, m_v_w+mj*144,
            m_ig_b+mj*2, m_fg_b+mj*2, m_skip+mj*36, m_on_w+mj*36,
            m_down_w+mj*648);
      ++mj;
    }
  }

  if (lane<48){
    #define OS(I) + elc<I>(x)
    const float mu = (0.f L18(OS))*(1.f/18.f);
    #undef OS
    #define OV(I) + sqf(elc<I>(x)-mu)
    const float var = (0.f L18(OV))*(1.f/18.f);
    #undef OV
    const float rr = rsqrtf(var+1e-5f);
    float acc = dense_b[0];
    #define OD(I) acc += (elc<I>(x)-mu)*rr*post_ln_w[I]*dense_w[I];
    L18(OD)
    #undef OD
    gout[b*48+lane] = (lane<24) ? 0.f : acc;
  }
}

extern "C" void kernel_launch(void* const* d_in, const int* in_sizes, int n_in,
                              void* d_out, int out_size, void* d_ws, size_t ws_size,
                              hipStream_t stream)
{
  const float* gx        = (const float*)d_in[0];
  const float* m_ln_w    = (const float*)d_in[1];
  const float* m_up_w    = (const float*)d_in[2];
  const float* m_conv_w  = (const float*)d_in[3];
  const float* m_conv_b  = (const float*)d_in[4];
  const float* m_q_w     = (const float*)d_in[5];
  const float* m_k_w     = (const float*)d_in[6];
  const float* m_v_w     = (const float*)d_in[7];
  const float* m_ig_w    = (const float*)d_in[8];
  const float* m_ig_b    = (const float*)d_in[9];
  const float* m_fg_w    = (const float*)d_in[10];
  const float* m_fg_b    = (const float*)d_in[11];
  const float* m_skip    = (const float*)d_in[12];
  const float* m_on_w    = (const float*)d_in[13];
  const float* m_down_w  = (const float*)d_in[14];
  const float* s_ln_w    = (const float*)d_in[15];
  const float* s_conv_w  = (const float*)d_in[16];
  const float* s_conv_b  = (const float*)d_in[17];
  const float* s_gate_w  = (const float*)d_in[18];
  const float* s_rec_w   = (const float*)d_in[19];
  const float* s_bias    = (const float*)d_in[20];
  const float* s_gn_w    = (const float*)d_in[21];
  const float* f_ln_w    = (const float*)d_in[22];
  const float* f_up_w    = (const float*)d_in[23];
  const float* f_down_w  = (const float*)d_in[24];
  const float* post_ln_w = (const float*)d_in[25];
  const float* dense_w   = (const float*)d_in[26];
  const float* dense_b   = (const float*)d_in[27];

  float* W = (float*)d_ws;
  const int B = in_sizes[0] / (48*18);

  prep_kernel<<<1, 256, 0, stream>>>(m_up_w, m_q_w, m_k_w, m_v_w, m_ig_w, m_fg_w,
                                     f_up_w, W);
  xlstm_kernel<<<(B+WPB-1)/WPB, TPB, 0, stream>>>(gx,
    m_ln_w, m_conv_w, m_conv_b, m_q_w, m_k_w, m_v_w,
    m_ig_b, m_fg_b, m_skip, m_on_w, m_down_w,
    s_ln_w, s_conv_w, s_conv_b, s_gate_w, s_rec_w, s_bias, s_gn_w,
    f_ln_w, f_down_w, post_ln_w, dense_w, dense_b, W, (float*)d_out, B);
}

// Round 17
// 1720.361 us; speedup vs baseline: 1.0100x; 1.0100x over previous
//
#include <hip/hip_runtime.h>
#include <math.h>

#define TPB 256
#define WPB 4

// per-wave LDS floats: KV[48][38] (K bf16 36 | V bf16 36 | 2 pad) + SZ bf16[48][36]
// KV row ushorts: K = c (0..35), V = 36+c (36..71), pad 72..75
constexpr int WAVE_F = 2688;          // 1824 + 864 ; block = 4*2688*4 = 43008 B -> 3 blocks/CU
constexpr int O_SZ   = 1824;

// d_ws weight-table offsets (floats)
constexpr int OW_UP  = 0;       // [6][72][18] up-proj transposed
constexpr int OW_AB  = 7776;    // [6][4][2][36] gate fold
constexpr int OW_FUP = 9504;    // [128][18] FFN up transposed

__device__ __forceinline__ float sigm(float v){ return 1.f/(1.f+__expf(-v)); }
__device__ __forceinline__ float siluf(float v){ return v/(1.f+__expf(-v)); }
__device__ __forceinline__ float logsig(float v){ return fminf(v,0.f) - log1pf(__expf(-fabsf(v))); }
__device__ __forceinline__ float sqf(float v){ return v*v; }
__device__ __forceinline__ unsigned short f2b(float v){
  union{float f; unsigned u;} c; c.f=v; unsigned u=c.u;
  return (unsigned short)((u + 0x7FFFu + ((u>>16)&1u))>>16);
}
__device__ __forceinline__ float b2f(unsigned short s){
  union{unsigned u; float f;} c; c.u=((unsigned)s)<<16; return c.f;
}
__device__ __forceinline__ float u2f(unsigned u){
  union{unsigned u; float f;} c; c.u=u; return c.f;
}
__device__ __forceinline__ unsigned packbf(float a, float b){
  return (unsigned)f2b(a) | ((unsigned)f2b(b)<<16);
}

struct V18 { float4 a,b,c,d; float2 e; };
struct U9  { unsigned u0,u1,u2,u3,u4,u5,u6,u7,u8; };

template<int I> __device__ __forceinline__ float elc(const V18& v){
  if constexpr(I==0) return v.a.x; else if constexpr(I==1) return v.a.y;
  else if constexpr(I==2) return v.a.z; else if constexpr(I==3) return v.a.w;
  else if constexpr(I==4) return v.b.x; else if constexpr(I==5) return v.b.y;
  else if constexpr(I==6) return v.b.z; else if constexpr(I==7) return v.b.w;
  else if constexpr(I==8) return v.c.x; else if constexpr(I==9) return v.c.y;
  else if constexpr(I==10) return v.c.z; else if constexpr(I==11) return v.c.w;
  else if constexpr(I==12) return v.d.x; else if constexpr(I==13) return v.d.y;
  else if constexpr(I==14) return v.d.z; else if constexpr(I==15) return v.d.w;
  else if constexpr(I==16) return v.e.x; else return v.e.y;
}
template<int I> __device__ __forceinline__ void setv(V18& v, float x){
  if constexpr(I==0) v.a.x=x; else if constexpr(I==1) v.a.y=x;
  else if constexpr(I==2) v.a.z=x; else if constexpr(I==3) v.a.w=x;
  else if constexpr(I==4) v.b.x=x; else if constexpr(I==5) v.b.y=x;
  else if constexpr(I==6) v.b.z=x; else if constexpr(I==7) v.b.w=x;
  else if constexpr(I==8) v.c.x=x; else if constexpr(I==9) v.c.y=x;
  else if constexpr(I==10) v.c.z=x; else if constexpr(I==11) v.c.w=x;
  else if constexpr(I==12) v.d.x=x; else if constexpr(I==13) v.d.y=x;
  else if constexpr(I==14) v.d.z=x; else if constexpr(I==15) v.d.w=x;
  else if constexpr(I==16) v.e.x=x; else v.e.y=x;
}
template<int J> __device__ __forceinline__ void setU(U9& p, unsigned v){
  if constexpr(J==0) p.u0=v; else if constexpr(J==1) p.u1=v;
  else if constexpr(J==2) p.u2=v; else if constexpr(J==3) p.u3=v;
  else if constexpr(J==4) p.u4=v; else if constexpr(J==5) p.u5=v;
  else if constexpr(J==6) p.u6=v; else if constexpr(J==7) p.u7=v;
  else p.u8=v;
}

__device__ __forceinline__ float dot18(const V18& h, const float* __restrict__ w){
  return h.a.x*w[0]+h.a.y*w[1]+h.a.z*w[2]+h.a.w*w[3]
       + h.b.x*w[4]+h.b.y*w[5]+h.b.z*w[6]+h.b.w*w[7]
       + h.c.x*w[8]+h.c.y*w[9]+h.c.z*w[10]+h.c.w*w[11]
       + h.d.x*w[12]+h.d.y*w[13]+h.d.z*w[14]+h.d.w*w[15]
       + h.e.x*w[16]+h.e.y*w[17];
}
__device__ __forceinline__ void axpy18(V18& x, float s, const float* __restrict__ w){
  x.a.x+=s*w[0];  x.a.y+=s*w[1];  x.a.z+=s*w[2];  x.a.w+=s*w[3];
  x.b.x+=s*w[4];  x.b.y+=s*w[5];  x.b.z+=s*w[6];  x.b.w+=s*w[7];
  x.c.x+=s*w[8];  x.c.y+=s*w[9];  x.c.z+=s*w[10]; x.c.w+=s*w[11];
  x.d.x+=s*w[12]; x.d.y+=s*w[13]; x.d.z+=s*w[14]; x.d.w+=s*w[15];
  x.e.x+=s*w[16]; x.e.y+=s*w[17];
}

#define L18(M) M(0) M(1) M(2) M(3) M(4) M(5) M(6) M(7) M(8) M(9) M(10) M(11) M(12) M(13) M(14) M(15) M(16) M(17)
#define L9(M) M(0) M(1) M(2) M(3) M(4) M(5) M(6) M(7) M(8)

extern "C" __global__ void prep_kernel(
    const float* __restrict__ up,  const float* __restrict__ qw, const float* __restrict__ kw,
    const float* __restrict__ vw,  const float* __restrict__ igw,const float* __restrict__ fgw,
    const float* __restrict__ fup, float* __restrict__ W)
{
  const int tid = threadIdx.x;
  for (int i=tid;i<7776;i+=256){ int mj=i/1296, r=i%1296, o=r/18, d=r%18; W[OW_UP+i]=up[mj*1296+d*72+o]; }
  for (int i=tid;i<1728;i+=256){
    int mj=i/288, r=i%288, gh=r/72, w2=(r%72)/36, c=r%36;
    int g=gh>>1,h=gh&1,n=c>>2,d=c&3;
    const float* gwp=(g? fgw:igw)+mj*216+h*108;
    float val=0.f;
    if(w2==0){ for(int o=0;o<4;++o) val += qw[mj*144+n*16+o*4+d]*gwp[n*4+o] + kw[mj*144+n*16+o*4+d]*gwp[36+n*4+o]; }
    else     { for(int o=0;o<4;++o) val += vw[mj*144+n*16+o*4+d]*gwp[72+n*4+o]; }
    W[OW_AB+i]=val;
  }
  for (int i=tid;i<2304;i+=256){ int f=i/18, d=i%18; W[OW_FUP+i]=fup[d*128+f]; }
}

template<int G>
__device__ __forceinline__ void proj_g(const V18& h, V18& x, U9& qp0, U9& qp1,
    float* kvrow, unsigned short* szrow, int lane,
    const float* __restrict__ wup, const float* __restrict__ wab,
    const float* __restrict__ cw,  const float* __restrict__ cb,
    const float* __restrict__ qw,  const float* __restrict__ kw, const float* __restrict__ vw,
    const float* __restrict__ skp, const float* __restrict__ dwn,
    float& gi0, float& gi1, float& gf0, float& gf1)
{
  constexpr int C0=4*G;
  float m0=dot18(h,wup+(C0+0)*18), m1=dot18(h,wup+(C0+1)*18),
        m2=dot18(h,wup+(C0+2)*18), m3=dot18(h,wup+(C0+3)*18);
  if(lane>=48){ m0=0.f;m1=0.f;m2=0.f;m3=0.f; }
  float c0,c1,c2,c3;
  { float p1=__shfl(m0,lane-1),p2=__shfl(m0,lane-2),p3=__shfl(m0,lane-3);
    c0=siluf(cb[C0+0]+p3*cw[(C0+0)*4]+p2*cw[(C0+0)*4+1]+p1*cw[(C0+0)*4+2]+m0*cw[(C0+0)*4+3]); }
  { float p1=__shfl(m1,lane-1),p2=__shfl(m1,lane-2),p3=__shfl(m1,lane-3);
    c1=siluf(cb[C0+1]+p3*cw[(C0+1)*4]+p2*cw[(C0+1)*4+1]+p1*cw[(C0+1)*4+2]+m1*cw[(C0+1)*4+3]); }
  { float p1=__shfl(m2,lane-1),p2=__shfl(m2,lane-2),p3=__shfl(m2,lane-3);
    c2=siluf(cb[C0+2]+p3*cw[(C0+2)*4]+p2*cw[(C0+2)*4+1]+p1*cw[(C0+2)*4+2]+m2*cw[(C0+2)*4+3]); }
  { float p1=__shfl(m3,lane-1),p2=__shfl(m3,lane-2),p3=__shfl(m3,lane-3);
    c3=siluf(cb[C0+3]+p3*cw[(C0+3)*4]+p2*cw[(C0+3)*4+1]+p1*cw[(C0+3)*4+2]+m3*cw[(C0+3)*4+3]); }
  const float s0=siluf(dot18(h,wup+(36+C0+0)*18));
  const float s1=siluf(dot18(h,wup+(36+C0+1)*18));
  const float s2=siluf(dot18(h,wup+(36+C0+2)*18));
  const float s3=siluf(dot18(h,wup+(36+C0+3)*18));
  gi0 += c0*wab[C0+0]+c1*wab[C0+1]+c2*wab[C0+2]+c3*wab[C0+3]
       + m0*wab[36+C0+0]+m1*wab[36+C0+1]+m2*wab[36+C0+2]+m3*wab[36+C0+3];
  gi1 += c0*wab[72+C0+0]+c1*wab[72+C0+1]+c2*wab[72+C0+2]+c3*wab[72+C0+3]
       + m0*wab[108+C0+0]+m1*wab[108+C0+1]+m2*wab[108+C0+2]+m3*wab[108+C0+3];
  gf0 += c0*wab[144+C0+0]+c1*wab[144+C0+1]+c2*wab[144+C0+2]+c3*wab[144+C0+3]
       + m0*wab[180+C0+0]+m1*wab[180+C0+1]+m2*wab[180+C0+2]+m3*wab[180+C0+3];
  gf1 += c0*wab[216+C0+0]+c1*wab[216+C0+1]+c2*wab[216+C0+2]+c3*wab[216+C0+3]
       + m0*wab[252+C0+0]+m1*wab[252+C0+1]+m2*wab[252+C0+2]+m3*wab[252+C0+3];
  if(lane<48){
    uint2 ss; ss.x=packbf(s0,s1); ss.y=packbf(s2,s3);
    *reinterpret_cast<uint2*>(reinterpret_cast<unsigned*>(szrow) + (C0>>1)) = ss;
    const float kt0=c0*kw[G*16+0] +c1*kw[G*16+1] +c2*kw[G*16+2] +c3*kw[G*16+3];
    const float kt1=c0*kw[G*16+4] +c1*kw[G*16+5] +c2*kw[G*16+6] +c3*kw[G*16+7];
    const float kt2=c0*kw[G*16+8] +c1*kw[G*16+9] +c2*kw[G*16+10]+c3*kw[G*16+11];
    const float kt3=c0*kw[G*16+12]+c1*kw[G*16+13]+c2*kw[G*16+14]+c3*kw[G*16+15];
    const float vt0=m0*vw[G*16+0] +m1*vw[G*16+1] +m2*vw[G*16+2] +m3*vw[G*16+3];
    const float vt1=m0*vw[G*16+4] +m1*vw[G*16+5] +m2*vw[G*16+6] +m3*vw[G*16+7];
    const float vt2=m0*vw[G*16+8] +m1*vw[G*16+9] +m2*vw[G*16+10]+m3*vw[G*16+11];
    const float vt3=m0*vw[G*16+12]+m1*vw[G*16+13]+m2*vw[G*16+14]+m3*vw[G*16+15];
    unsigned* urow = reinterpret_cast<unsigned*>(kvrow);
    uint2 kk2; kk2.x=packbf(kt0,kt1); kk2.y=packbf(kt2,kt3);
    *reinterpret_cast<uint2*>(urow + 2*G) = kk2;
    uint2 vv2; vv2.x=packbf(vt0,vt1); vv2.y=packbf(vt2,vt3);
    *reinterpret_cast<uint2*>(urow + 18 + 2*G) = vv2;
  }
  // q packed bf16 in registers (9 uints per head)
  const float qt0=c0*qw[G*16+0] +c1*qw[G*16+1] +c2*qw[G*16+2] +c3*qw[G*16+3];
  const float qt1=c0*qw[G*16+4] +c1*qw[G*16+5] +c2*qw[G*16+6] +c3*qw[G*16+7];
  const float qt2=c0*qw[G*16+8] +c1*qw[G*16+9] +c2*qw[G*16+10]+c3*qw[G*16+11];
  const float qt3=c0*qw[G*16+12]+c1*qw[G*16+13]+c2*qw[G*16+14]+c3*qw[G*16+15];
  const unsigned pq0 = packbf(qt0,qt1), pq1 = packbf(qt2,qt3);
  if constexpr(G<4){ setU<2*G>(qp0,pq0); setU<2*G+1>(qp0,pq1); }
  else if constexpr(G==4){ setU<8>(qp0,pq0); setU<0>(qp1,pq1); }
  else { setU<2*G-9>(qp1,pq0); setU<2*G-8>(qp1,pq1); }
  axpy18(x, skp[C0+0]*c0*s0, dwn+(C0+0)*18);
  axpy18(x, skp[C0+1]*c1*s1, dwn+(C0+1)*18);
  axpy18(x, skp[C0+2]*c2*s2, dwn+(C0+2)*18);
  axpy18(x, skp[C0+3]*c3*s3, dwn+(C0+3)*18);
}

#define UNP(u, lo, hi) const float lo = u2f((u)<<16); const float hi = u2f((u)&0xffff0000u);

template<int HH>
__device__ __forceinline__ void attn_fold(const U9& qp, V18& x, int lane,
    const float* KV, const unsigned short* szrow,
    float ipt, float lf, float u,
    const float* __restrict__ onw, const float* __restrict__ dwn)
{
  // unpack own-head q (bf16 -> f32) once
  UNP(qp.u0,q0,q1)   UNP(qp.u1,q2,q3)   UNP(qp.u2,q4,q5)
  UNP(qp.u3,q6,q7)   UNP(qp.u4,q8,q9)   UNP(qp.u5,q10,q11)
  UNP(qp.u6,q12,q13) UNP(qp.u7,q14,q15) UNP(qp.u8,q16,q17)

  V18 acc;
  { float4 z4{0.f,0.f,0.f,0.f}; acc.a=z4; acc.b=z4; acc.c=z4; acc.d=z4; acc.e.x=0.f; acc.e.y=0.f; }
  float rs=0.f;
  const float rb=-u;
  const float scl=0.23570226039551584f;
  for(int t=0;t<48;++t){
    const float ipx = __shfl(ipt, t);
    const unsigned* ur = reinterpret_cast<const unsigned*>(KV + t*38);
    constexpr int KB = HH? 9 : 0;      // uint offset of this head's K
    const unsigned a0=ur[KB+0], a1=ur[KB+1], a2=ur[KB+2], a3=ur[KB+3], a4=ur[KB+4],
                   a5=ur[KB+5], a6=ur[KB+6], a7=ur[KB+7], a8=ur[KB+8];
    UNP(a0,k0,k1) UNP(a1,k2,k3) UNP(a2,k4,k5) UNP(a3,k6,k7) UNP(a4,k8,k9)
    UNP(a5,k10,k11) UNP(a6,k12,k13) UNP(a7,k14,k15) UNP(a8,k16,k17)
    const float qk = k0*q0+k1*q1+k2*q2+k3*q3+k4*q4+k5*q5+k6*q6+k7*q7+k8*q8
                   + k9*q9+k10*q10+k11*q11+k12*q12+k13*q13+k14*q14+k15*q15
                   + k16*q16+k17*q17;
    const float e0=__expf(fminf(rb+ipx,0.f));
    const float cc = (t<=lane)? qk*scl*e0 : 0.f;
    rs+=cc;
    constexpr int VB = HH? 27 : 18;    // uint offset of this head's V
    const unsigned b0=ur[VB+0], b1=ur[VB+1], b2=ur[VB+2], b3=ur[VB+3], b4=ur[VB+4],
                   b5=ur[VB+5], b6=ur[VB+6], b7=ur[VB+7], b8=ur[VB+8];
    UNP(b0,v0,v1) UNP(b1,v2,v3) UNP(b2,v4,v5) UNP(b3,v6,v7) UNP(b4,v8,v9)
    UNP(b5,v10,v11) UNP(b6,v12,v13) UNP(b7,v14,v15) UNP(b8,v16,v17)
    acc.a.x+=cc*v0;  acc.a.y+=cc*v1;  acc.a.z+=cc*v2;  acc.a.w+=cc*v3;
    acc.b.x+=cc*v4;  acc.b.y+=cc*v5;  acc.b.z+=cc*v6;  acc.b.w+=cc*v7;
    acc.c.x+=cc*v8;  acc.c.y+=cc*v9;  acc.c.z+=cc*v10; acc.c.w+=cc*v11;
    acc.d.x+=cc*v12; acc.d.y+=cc*v13; acc.d.z+=cc*v14; acc.d.w+=cc*v15;
    acc.e.x+=cc*v16; acc.e.y+=cc*v17;
  }
  const float mr = lf+u;
  const float ninv = 1.f/(fmaxf(fabsf(rs), __expf(-mr))+1e-6f);
  #define AS(I) + elc<I>(acc)
  const float mb = (0.f L18(AS))*(1.f/18.f);
  #undef AS
  #define AV(I) + sqf(elc<I>(acc)-mb)
  const float vb2 = 0.f L18(AV);
  #undef AV
  const float rn = rsqrtf(ninv*ninv*vb2*(1.f/18.f)+1e-5f);
  #define FD(I) { const float hn=(elc<I>(acc)-mb)*ninv*rn*onw[HH*18+I]; \
                  axpy18(x, hn*b2f(szrow[HH*18+I]), dwn+(HH*18+I)*18); }
  L18(FD)
  #undef FD
}

__device__ __forceinline__ void mlstm(V18& x, int lane, float* WV, unsigned short* SZB,
    const float* __restrict__ lnw, const float* __restrict__ wup, const float* __restrict__ wab,
    const float* __restrict__ cw,  const float* __restrict__ cb,
    const float* __restrict__ qw,  const float* __restrict__ kw,  const float* __restrict__ vw,
    const float* __restrict__ igb, const float* __restrict__ fgb, const float* __restrict__ skp,
    const float* __restrict__ onw, const float* __restrict__ dwn)
{
  #define MS(I) + elc<I>(x)
  const float mu = (0.f L18(MS))*(1.f/18.f);
  #undef MS
  #define MV(I) + sqf(elc<I>(x)-mu)
  const float var = (0.f L18(MV))*(1.f/18.f);
  #undef MV
  const float rr = rsqrtf(var+1e-5f);
  V18 h;
  #define MH(I) setv<I>(h,(elc<I>(x)-mu)*rr*lnw[I]);
  L18(MH)
  #undef MH

  U9 qp0, qp1;
  float gi0=igb[0], gi1=igb[1], gf0=fgb[0], gf1=fgb[1];
  float* kvrow = WV + lane*38;
  const int sr = (lane<48)? lane : 0;
  unsigned short* szrow = SZB + sr*36;
  proj_g<0>(h,x,qp0,qp1,kvrow,szrow,lane,wup,wab,cw,cb,qw,kw,vw,skp,dwn,gi0,gi1,gf0,gf1);
  proj_g<1>(h,x,qp0,qp1,kvrow,szrow,lane,wup,wab,cw,cb,qw,kw,vw,skp,dwn,gi0,gi1,gf0,gf1);
  proj_g<2>(h,x,qp0,qp1,kvrow,szrow,lane,wup,wab,cw,cb,qw,kw,vw,skp,dwn,gi0,gi1,gf0,gf1);
  proj_g<3>(h,x,qp0,qp1,kvrow,szrow,lane,wup,wab,cw,cb,qw,kw,vw,skp,dwn,gi0,gi1,gf0,gf1);
  proj_g<4>(h,x,qp0,qp1,kvrow,szrow,lane,wup,wab,cw,cb,qw,kw,vw,skp,dwn,gi0,gi1,gf0,gf1);
  proj_g<5>(h,x,qp0,qp1,kvrow,szrow,lane,wup,wab,cw,cb,qw,kw,vw,skp,dwn,gi0,gi1,gf0,gf1);
  proj_g<6>(h,x,qp0,qp1,kvrow,szrow,lane,wup,wab,cw,cb,qw,kw,vw,skp,dwn,gi0,gi1,gf0,gf1);
  proj_g<7>(h,x,qp0,qp1,kvrow,szrow,lane,wup,wab,cw,cb,qw,kw,vw,skp,dwn,gi0,gi1,gf0,gf1);
  proj_g<8>(h,x,qp0,qp1,kvrow,szrow,lane,wup,wab,cw,cb,qw,kw,vw,skp,dwn,gi0,gi1,gf0,gf1);

  float lf0=logsig(gf0), lf1=logsig(gf1);
  #pragma unroll
  for(int off=1; off<64; off<<=1){
    float t0=__shfl_up(lf0,off), t1=__shfl_up(lf1,off);
    if(lane>=off){ lf0+=t0; lf1+=t1; }
  }
  const float ipt0=gi0-lf0, ipt1=gi1-lf1;
  float u0=ipt0, u1=ipt1;
  #pragma unroll
  for(int off=1; off<64; off<<=1){
    float t0=__shfl_up(u0,off), t1=__shfl_up(u1,off);
    if(lane>=off){ u0=fmaxf(u0,t0); u1=fmaxf(u1,t1); }
  }
  asm volatile("s_waitcnt lgkmcnt(0)" ::: "memory");

  attn_fold<0>(qp0, x, lane, WV, szrow, ipt0, lf0, u0, onw, dwn);
  attn_fold<1>(qp1, x, lane, WV, szrow, ipt1, lf1, u1, onw, dwn);
}

// sLSTM scan for one head: wx computed on the fly via __shfl broadcasts of h/hc.
template<int HH>
__device__ __forceinline__ void scan_head(const V18& h, const V18& hc, int lane, float* Y,
    const float* __restrict__ gw, const float* __restrict__ gb, const float* __restrict__ rw)
{
  const int li = (lane<36)? lane : 0;
  const int g=li/9, e=li%9;
  const float* gwb = gw + ((g*2+HH)*9+e)*9;
  const float w0=gwb[0],w1=gwb[1],w2=gwb[2],w3=gwb[3],w4=gwb[4],
              w5=gwb[5],w6=gwb[6],w7=gwb[7],w8=gwb[8];
  const float bias = gb[(g*2+HH)*9+e];
  const float* rwb = rw + HH*324 + g*9 + e;
  const float r0=rwb[0], r1=rwb[36], r2=rwb[72], r3=rwb[108], r4=rwb[144],
              r5=rwb[180], r6=rwb[216], r7=rwb[252], r8=rwb[288];
  const bool usehc = (g<2);
  float yv=0.f,cv=0.f,nv=0.f,mv=0.f;
  for(int st=0; st<48; ++st){
    float raw = bias;
    #define BIN(D,W) { const float bh=__shfl(elc<9*HH+D>(h),st); \
                       const float bc=__shfl(elc<9*HH+D>(hc),st); \
                       raw += (usehc? bc : bh)*W; }
    BIN(0,w0) BIN(1,w1) BIN(2,w2) BIN(3,w3) BIN(4,w4) BIN(5,w5) BIN(6,w6) BIN(7,w7) BIN(8,w8)
    #undef BIN
    raw += __shfl(yv,0)*r0 + __shfl(yv,1)*r1 + __shfl(yv,2)*r2
         + __shfl(yv,3)*r3 + __shfl(yv,4)*r4 + __shfl(yv,5)*r5
         + __shfl(yv,6)*r6 + __shfl(yv,7)*r7 + __shfl(yv,8)*r8;
    const float i_=__shfl(raw,e), f_=__shfl(raw,9+e), z_=__shfl(raw,18+e), o_=__shfl(raw,27+e);
    const float lfm=mv+logsig(f_);
    const float mn=fmaxf(i_,lfm);
    const float ig=__expf(i_-mn), fg=__expf(lfm-mn);
    const float th=1.f-2.f/(__expf(2.f*z_)+1.f);
    cv=fg*cv+ig*th;
    nv=fg*nv+ig; mv=mn;
    yv=sigm(o_)*cv/nv;
    if(lane<9) Y[st*18 + HH*9 + lane] = yv;
  }
}

__device__ __forceinline__ void slstm(V18& x, int lane, float* Y,
    const float* __restrict__ lnw, const float* __restrict__ cw, const float* __restrict__ cb,
    const float* __restrict__ gw,  const float* __restrict__ rw, const float* __restrict__ gb,
    const float* __restrict__ gnw, const float* __restrict__ flnw,
    const float* __restrict__ wfup,const float* __restrict__ fdw)
{
  #define SS(I) + elc<I>(x)
  const float mu = (0.f L18(SS))*(1.f/18.f);
  #undef SS
  #define SV(I) + sqf(elc<I>(x)-mu)
  const float var = (0.f L18(SV))*(1.f/18.f);
  #undef SV
  const float rr = rsqrtf(var+1e-5f);
  V18 h;
  #define SH(I) setv<I>(h,(lane<48)?(elc<I>(x)-mu)*rr*lnw[I]:0.f);
  L18(SH)
  #undef SH
  V18 hc;
  #define SC(I) { const float hv=elc<I>(h); \
    const float p1=__shfl(hv,lane-1),p2=__shfl(hv,lane-2),p3=__shfl(hv,lane-3); \
    setv<I>(hc, siluf(cb[I]+p3*cw[(I)*4]+p2*cw[(I)*4+1]+p1*cw[(I)*4+2]+hv*cw[(I)*4+3])); }
  L18(SC)
  #undef SC

  scan_head<0>(h, hc, lane, Y, gw, gb, rw);
  scan_head<1>(h, hc, lane, Y, gw, gb, rw);
  asm volatile("s_waitcnt lgkmcnt(0)" ::: "memory");

  if(lane<48){
    {
      float m2=0.f;
      for(int e=0;e<9;++e) m2+=Y[lane*18+e];
      m2*=(1.f/9.f);
      float vv=0.f;
      for(int e=0;e<9;++e){ float t=Y[lane*18+e]-m2; vv+=t*t; }
      const float r2=rsqrtf(vv*(1.f/9.f)+1e-5f);
      #define GN0(E) setv<E>(x, elc<E>(x)+(Y[lane*18+E]-m2)*r2*gnw[E]);
      L9(GN0)
      #undef GN0
    }
    {
      float m2=0.f;
      for(int e=0;e<9;++e) m2+=Y[lane*18+9+e];
      m2*=(1.f/9.f);
      float vv=0.f;
      for(int e=0;e<9;++e){ float t=Y[lane*18+9+e]-m2; vv+=t*t; }
      const float r2=rsqrtf(vv*(1.f/9.f)+1e-5f);
      #define GN1(E) setv<(9+E)>(x, elc<(9+E)>(x)+(Y[lane*18+9+E]-m2)*r2*gnw[9+E]);
      L9(GN1)
      #undef GN1
    }
  }

  #define FS(I) + elc<I>(x)
  const float mu2 = (0.f L18(FS))*(1.f/18.f);
  #undef FS
  #define FV(I) + sqf(elc<I>(x)-mu2)
  const float var2 = (0.f L18(FV))*(1.f/18.f);
  #undef FV
  const float rr2 = rsqrtf(var2+1e-5f);
  V18 h2;
  #define FH(I) setv<I>(h2,(elc<I>(x)-mu2)*rr2*flnw[I]);
  L18(FH)
  #undef FH
  for(int f=0;f<64;++f){
    const float ug=dot18(h2, wfup+f*18);
    const float uu=dot18(h2, wfup+(64+f)*18);
    const float ge=0.5f*ug*(1.f+erff(ug*0.70710678118654752f));
    axpy18(x, ge*uu, fdw+f*18);
  }
}

extern "C" __global__ void __launch_bounds__(TPB)
xlstm_kernel(const float* __restrict__ gx,
             const float* __restrict__ m_ln_w,  const float* __restrict__ m_conv_w,
             const float* __restrict__ m_conv_b,const float* __restrict__ m_q_w,
             const float* __restrict__ m_k_w,   const float* __restrict__ m_v_w,
             const float* __restrict__ m_ig_b,  const float* __restrict__ m_fg_b,
             const float* __restrict__ m_skip,  const float* __restrict__ m_on_w,
             const float* __restrict__ m_down_w,
             const float* __restrict__ s_ln_w,  const float* __restrict__ s_conv_w,
             const float* __restrict__ s_conv_b,const float* __restrict__ s_gate_w,
             const float* __restrict__ s_rec_w, const float* __restrict__ s_bias,
             const float* __restrict__ s_gn_w,  const float* __restrict__ f_ln_w,
             const float* __restrict__ f_down_w,
             const float* __restrict__ post_ln_w, const float* __restrict__ dense_w,
             const float* __restrict__ dense_b, const float* __restrict__ W,
             float* __restrict__ gout, const int Btot)
{
  __shared__ float L[WPB*WAVE_F];
  const int lane = threadIdx.x & 63;
  const int wv   = threadIdx.x >> 6;
  const int b    = blockIdx.x*WPB + wv;
  if (b >= Btot) return;
  float* WV = L + wv*WAVE_F;
  unsigned short* SZB = reinterpret_cast<unsigned short*>(WV + O_SZ);

  V18 x;
  const float* gxb = gx + b*864 + lane*18;
  #define XL(I) setv<I>(x,(lane<48)? gxb[I] : 0.f);
  L18(XL)
  #undef XL

  int mj=0;
  #pragma unroll 1
  for(int blk=0; blk<7; ++blk){
    if (blk==1){
      slstm(x, lane, WV, s_ln_w, s_conv_w, s_conv_b, s_gate_w, s_rec_w, s_bias,
            s_gn_w, f_ln_w, W+OW_FUP, f_down_w);
    } else {
      mlstm(x, lane, WV, SZB,
            m_ln_w+mj*18, W+OW_UP+mj*1296, W+OW_AB+mj*288,
            m_conv_w+mj*144, m_conv_b+mj*36,
            m_q_w+mj*144, m_k_w+mj*144, m_v_w+mj*144,
            m_ig_b+mj*2, m_fg_b+mj*2, m_skip+mj*36, m_on_w+mj*36,
            m_down_w+mj*648);
      ++mj;
    }
  }

  if (lane<48){
    #define OS(I) + elc<I>(x)
    const float mu = (0.f L18(OS))*(1.f/18.f);
    #undef OS
    #define OV(I) + sqf(elc<I>(x)-mu)
    const float var = (0.f L18(OV))*(1.f/18.f);
    #undef OV
    const float rr = rsqrtf(var+1e-5f);
    float acc = dense_b[0];
    #define OD(I) acc += (elc<I>(x)-mu)*rr*post_ln_w[I]*dense_w[I];
    L18(OD)
    #undef OD
    gout[b*48+lane] = (lane<24) ? 0.f : acc;
  }
}

extern "C" void kernel_launch(void* const* d_in, const int* in_sizes, int n_in,
                              void* d_out, int out_size, void* d_ws, size_t ws_size,
                              hipStream_t stream)
{
  const float* gx        = (const float*)d_in[0];
  const float* m_ln_w    = (const float*)d_in[1];
  const float* m_up_w    = (const float*)d_in[2];
  const float* m_conv_w  = (const float*)d_in[3];
  const float* m_conv_b  = (const float*)d_in[4];
  const float* m_q_w     = (const float*)d_in[5];
  const float* m_k_w     = (const float*)d_in[6];
  const float* m_v_w     = (const float*)d_in[7];
  const float* m_ig_w    = (const float*)d_in[8];
  const float* m_ig_b    = (const float*)d_in[9];
  const float* m_fg_w    = (const float*)d_in[10];
  const float* m_fg_b    = (const float*)d_in[11];
  const float* m_skip    = (const float*)d_in[12];
  const float* m_on_w    = (const float*)d_in[13];
  const float* m_down_w  = (const float*)d_in[14];
  const float* s_ln_w    = (const float*)d_in[15];
  const float* s_conv_w  = (const float*)d_in[16];
  const float* s_conv_b  = (const float*)d_in[17];
  const float* s_gate_w  = (const float*)d_in[18];
  const float* s_rec_w   = (const float*)d_in[19];
  const float* s_bias    = (const float*)d_in[20];
  const float* s_gn_w    = (const float*)d_in[21];
  const float* f_ln_w    = (const float*)d_in[22];
  const float* f_up_w    = (const float*)d_in[23];
  const float* f_down_w  = (const float*)d_in[24];
  const float* post_ln_w = (const float*)d_in[25];
  const float* dense_w   = (const float*)d_in[26];
  const float* dense_b   = (const float*)d_in[27];

  float* W = (float*)d_ws;
  const int B = in_sizes[0] / (48*18);

  prep_kernel<<<1, 256, 0, stream>>>(m_up_w, m_q_w, m_k_w, m_v_w, m_ig_w, m_fg_w,
                                     f_up_w, W);
  xlstm_kernel<<<(B+WPB-1)/WPB, TPB, 0, stream>>>(gx,
    m_ln_w, m_conv_w, m_conv_b, m_q_w, m_k_w, m_v_w,
    m_ig_b, m_fg_b, m_skip, m_on_w, m_down_w,
    s_ln_w, s_conv_w, s_conv_b, s_gate_w, s_rec_w, s_bias, s_gn_w,
    f_ln_w, f_down_w, post_ln_w, dense_w, dense_b, W, (float*)d_out, B);
}

// Round 18
// 1051.042 us; speedup vs baseline: 1.6532x; 1.6368x over previous
//
#include <hip/hip_runtime.h>
#include <math.h>

#define TPB 256
#define WPB 4

// per-wave LDS floats: KV[48][56] (K fp32 36 | V bf16 36 in 20 float slots) + SZ bf16[48][36]
constexpr int WAVE_F = 3552;          // 2688 + 864 ; block = 4*3552*4 = 56832 B -> 2 blocks/CU
constexpr int O_SZ   = 2688;

// d_ws weight-table offsets (floats)
constexpr int OW_UP  = 0;       // [6][72][18] up-proj transposed
constexpr int OW_AB  = 7776;    // [6][4][2][36] gate fold
constexpr int OW_FUP = 9504;    // [128][18] FFN up transposed

__device__ __forceinline__ float sigm(float v){ return 1.f/(1.f+__expf(-v)); }
__device__ __forceinline__ float siluf(float v){ return v/(1.f+__expf(-v)); }
__device__ __forceinline__ float logsig(float v){ return fminf(v,0.f) - log1pf(__expf(-fabsf(v))); }
__device__ __forceinline__ float sqf(float v){ return v*v; }
__device__ __forceinline__ unsigned short f2b(float v){
  union{float f; unsigned u;} c; c.f=v; unsigned u=c.u;
  return (unsigned short)((u + 0x7FFFu + ((u>>16)&1u))>>16);
}
__device__ __forceinline__ float b2f(unsigned short s){
  union{unsigned u; float f;} c; c.u=((unsigned)s)<<16; return c.f;
}
__device__ __forceinline__ float u2f(unsigned u){
  union{unsigned u; float f;} c; c.u=u; return c.f;
}
__device__ __forceinline__ unsigned packbf(float a, float b){
  return (unsigned)f2b(a) | ((unsigned)f2b(b)<<16);
}
__device__ __forceinline__ float dot4(const float4 a, const float4 b){
  return a.x*b.x+a.y*b.y+a.z*b.z+a.w*b.w;
}

struct V18 { float4 a,b,c,d; float2 e; };
struct V36 { float4 g0,g1,g2,g3,g4,g5,g6,g7,g8; };

template<int I> __device__ __forceinline__ float elc(const V18& v){
  if constexpr(I==0) return v.a.x; else if constexpr(I==1) return v.a.y;
  else if constexpr(I==2) return v.a.z; else if constexpr(I==3) return v.a.w;
  else if constexpr(I==4) return v.b.x; else if constexpr(I==5) return v.b.y;
  else if constexpr(I==6) return v.b.z; else if constexpr(I==7) return v.b.w;
  else if constexpr(I==8) return v.c.x; else if constexpr(I==9) return v.c.y;
  else if constexpr(I==10) return v.c.z; else if constexpr(I==11) return v.c.w;
  else if constexpr(I==12) return v.d.x; else if constexpr(I==13) return v.d.y;
  else if constexpr(I==14) return v.d.z; else if constexpr(I==15) return v.d.w;
  else if constexpr(I==16) return v.e.x; else return v.e.y;
}
template<int I> __device__ __forceinline__ void setv(V18& v, float x){
  if constexpr(I==0) v.a.x=x; else if constexpr(I==1) v.a.y=x;
  else if constexpr(I==2) v.a.z=x; else if constexpr(I==3) v.a.w=x;
  else if constexpr(I==4) v.b.x=x; else if constexpr(I==5) v.b.y=x;
  else if constexpr(I==6) v.b.z=x; else if constexpr(I==7) v.b.w=x;
  else if constexpr(I==8) v.c.x=x; else if constexpr(I==9) v.c.y=x;
  else if constexpr(I==10) v.c.z=x; else if constexpr(I==11) v.c.w=x;
  else if constexpr(I==12) v.d.x=x; else if constexpr(I==13) v.d.y=x;
  else if constexpr(I==14) v.d.z=x; else if constexpr(I==15) v.d.w=x;
  else if constexpr(I==16) v.e.x=x; else v.e.y=x;
}
template<int G> __device__ __forceinline__ float4& grp(V36& q){
  if constexpr(G==0) return q.g0; else if constexpr(G==1) return q.g1;
  else if constexpr(G==2) return q.g2; else if constexpr(G==3) return q.g3;
  else if constexpr(G==4) return q.g4; else if constexpr(G==5) return q.g5;
  else if constexpr(G==6) return q.g6; else if constexpr(G==7) return q.g7;
  else return q.g8;
}

__device__ __forceinline__ float dot18(const V18& h, const float* __restrict__ w){
  return h.a.x*w[0]+h.a.y*w[1]+h.a.z*w[2]+h.a.w*w[3]
       + h.b.x*w[4]+h.b.y*w[5]+h.b.z*w[6]+h.b.w*w[7]
       + h.c.x*w[8]+h.c.y*w[9]+h.c.z*w[10]+h.c.w*w[11]
       + h.d.x*w[12]+h.d.y*w[13]+h.d.z*w[14]+h.d.w*w[15]
       + h.e.x*w[16]+h.e.y*w[17];
}
__device__ __forceinline__ void axpy18(V18& x, float s, const float* __restrict__ w){
  x.a.x+=s*w[0];  x.a.y+=s*w[1];  x.a.z+=s*w[2];  x.a.w+=s*w[3];
  x.b.x+=s*w[4];  x.b.y+=s*w[5];  x.b.z+=s*w[6];  x.b.w+=s*w[7];
  x.c.x+=s*w[8];  x.c.y+=s*w[9];  x.c.z+=s*w[10]; x.c.w+=s*w[11];
  x.d.x+=s*w[12]; x.d.y+=s*w[13]; x.d.z+=s*w[14]; x.d.w+=s*w[15];
  x.e.x+=s*w[16]; x.e.y+=s*w[17];
}
template<int B> __device__ __forceinline__ float dot9(const V18& v, const float* __restrict__ w){
  return elc<B+0>(v)*w[0]+elc<B+1>(v)*w[1]+elc<B+2>(v)*w[2]+elc<B+3>(v)*w[3]
       + elc<B+4>(v)*w[4]+elc<B+5>(v)*w[5]+elc<B+6>(v)*w[6]+elc<B+7>(v)*w[7]
       + elc<B+8>(v)*w[8];
}

#define L18(M) M(0) M(1) M(2) M(3) M(4) M(5) M(6) M(7) M(8) M(9) M(10) M(11) M(12) M(13) M(14) M(15) M(16) M(17)
#define L9(M) M(0) M(1) M(2) M(3) M(4) M(5) M(6) M(7) M(8)

extern "C" __global__ void prep_kernel(
    const float* __restrict__ up,  const float* __restrict__ qw, const float* __restrict__ kw,
    const float* __restrict__ vw,  const float* __restrict__ igw,const float* __restrict__ fgw,
    const float* __restrict__ fup, float* __restrict__ W)
{
  const int tid = threadIdx.x;
  for (int i=tid;i<7776;i+=256){ int mj=i/1296, r=i%1296, o=r/18, d=r%18; W[OW_UP+i]=up[mj*1296+d*72+o]; }
  for (int i=tid;i<1728;i+=256){
    int mj=i/288, r=i%288, gh=r/72, w2=(r%72)/36, c=r%36;
    int g=gh>>1,h=gh&1,n=c>>2,d=c&3;
    const float* gwp=(g? fgw:igw)+mj*216+h*108;
    float val=0.f;
    if(w2==0){ for(int o=0;o<4;++o) val += qw[mj*144+n*16+o*4+d]*gwp[n*4+o] + kw[mj*144+n*16+o*4+d]*gwp[36+n*4+o]; }
    else     { for(int o=0;o<4;++o) val += vw[mj*144+n*16+o*4+d]*gwp[72+n*4+o]; }
    W[OW_AB+i]=val;
  }
  for (int i=tid;i<2304;i+=256){ int f=i/18, d=i%18; W[OW_FUP+i]=fup[d*128+f]; }
}

template<int G>
__device__ __forceinline__ void proj_g(const V18& h, V18& x, V36& q,
    float* kvrow, unsigned short* szrow, int lane,
    const float* __restrict__ wup, const float* __restrict__ wab,
    const float* __restrict__ cw,  const float* __restrict__ cb,
    const float* __restrict__ qw,  const float* __restrict__ kw, const float* __restrict__ vw,
    const float* __restrict__ skp, const float* __restrict__ dwn,
    float& gi0, float& gi1, float& gf0, float& gf1)
{
  constexpr int C0=4*G;
  float m0=dot18(h,wup+(C0+0)*18), m1=dot18(h,wup+(C0+1)*18),
        m2=dot18(h,wup+(C0+2)*18), m3=dot18(h,wup+(C0+3)*18);
  if(lane>=48){ m0=0.f;m1=0.f;m2=0.f;m3=0.f; }
  float c0,c1,c2,c3;
  { float p1=__shfl(m0,lane-1),p2=__shfl(m0,lane-2),p3=__shfl(m0,lane-3);
    c0=siluf(cb[C0+0]+p3*cw[(C0+0)*4]+p2*cw[(C0+0)*4+1]+p1*cw[(C0+0)*4+2]+m0*cw[(C0+0)*4+3]); }
  { float p1=__shfl(m1,lane-1),p2=__shfl(m1,lane-2),p3=__shfl(m1,lane-3);
    c1=siluf(cb[C0+1]+p3*cw[(C0+1)*4]+p2*cw[(C0+1)*4+1]+p1*cw[(C0+1)*4+2]+m1*cw[(C0+1)*4+3]); }
  { float p1=__shfl(m2,lane-1),p2=__shfl(m2,lane-2),p3=__shfl(m2,lane-3);
    c2=siluf(cb[C0+2]+p3*cw[(C0+2)*4]+p2*cw[(C0+2)*4+1]+p1*cw[(C0+2)*4+2]+m2*cw[(C0+2)*4+3]); }
  { float p1=__shfl(m3,lane-1),p2=__shfl(m3,lane-2),p3=__shfl(m3,lane-3);
    c3=siluf(cb[C0+3]+p3*cw[(C0+3)*4]+p2*cw[(C0+3)*4+1]+p1*cw[(C0+3)*4+2]+m3*cw[(C0+3)*4+3]); }
  const float s0=siluf(dot18(h,wup+(36+C0+0)*18));
  const float s1=siluf(dot18(h,wup+(36+C0+1)*18));
  const float s2=siluf(dot18(h,wup+(36+C0+2)*18));
  const float s3=siluf(dot18(h,wup+(36+C0+3)*18));
  gi0 += c0*wab[C0+0]+c1*wab[C0+1]+c2*wab[C0+2]+c3*wab[C0+3]
       + m0*wab[36+C0+0]+m1*wab[36+C0+1]+m2*wab[36+C0+2]+m3*wab[36+C0+3];
  gi1 += c0*wab[72+C0+0]+c1*wab[72+C0+1]+c2*wab[72+C0+2]+c3*wab[72+C0+3]
       + m0*wab[108+C0+0]+m1*wab[108+C0+1]+m2*wab[108+C0+2]+m3*wab[108+C0+3];
  gf0 += c0*wab[144+C0+0]+c1*wab[144+C0+1]+c2*wab[144+C0+2]+c3*wab[144+C0+3]
       + m0*wab[180+C0+0]+m1*wab[180+C0+1]+m2*wab[180+C0+2]+m3*wab[180+C0+3];
  gf1 += c0*wab[216+C0+0]+c1*wab[216+C0+1]+c2*wab[216+C0+2]+c3*wab[216+C0+3]
       + m0*wab[252+C0+0]+m1*wab[252+C0+1]+m2*wab[252+C0+2]+m3*wab[252+C0+3];
  if(lane<48){
    // SZ bf16 (uint2: 8B aligned since row base = sr*72B, C0*2 % 8 == 0)
    uint2 ss; ss.x=packbf(s0,s1); ss.y=packbf(s2,s3);
    *reinterpret_cast<uint2*>(reinterpret_cast<unsigned*>(szrow) + (C0>>1)) = ss;
    // K fp32 contiguous [0,36)
    float4 kk;
    kk.x=c0*kw[G*16+0] +c1*kw[G*16+1] +c2*kw[G*16+2] +c3*kw[G*16+3];
    kk.y=c0*kw[G*16+4] +c1*kw[G*16+5] +c2*kw[G*16+6] +c3*kw[G*16+7];
    kk.z=c0*kw[G*16+8] +c1*kw[G*16+9] +c2*kw[G*16+10]+c3*kw[G*16+11];
    kk.w=c0*kw[G*16+12]+c1*kw[G*16+13]+c2*kw[G*16+14]+c3*kw[G*16+15];
    *reinterpret_cast<float4*>(kvrow + C0) = kk;
    // V bf16: head0 at ushort 72+idx, head1 at ushort 92+idx
    float vt0=m0*vw[G*16+0] +m1*vw[G*16+1] +m2*vw[G*16+2] +m3*vw[G*16+3];
    float vt1=m0*vw[G*16+4] +m1*vw[G*16+5] +m2*vw[G*16+6] +m3*vw[G*16+7];
    float vt2=m0*vw[G*16+8] +m1*vw[G*16+9] +m2*vw[G*16+10]+m3*vw[G*16+11];
    float vt3=m0*vw[G*16+12]+m1*vw[G*16+13]+m2*vw[G*16+14]+m3*vw[G*16+15];
    unsigned* urow = reinterpret_cast<unsigned*>(kvrow);
    if constexpr(G<4){
      uint2 vv; vv.x=packbf(vt0,vt1); vv.y=packbf(vt2,vt3);
      *reinterpret_cast<uint2*>(urow + 36 + 2*G) = vv;
    } else if constexpr(G==4){
      urow[44] = packbf(vt0,vt1);     // c16,17 (head0 idx 16,17)
      urow[46] = packbf(vt2,vt3);     // c18,19 (head1 idx 0,1)
    } else {
      urow[37+2*G] = packbf(vt0,vt1); // head1 idx 4G-18..
      urow[38+2*G] = packbf(vt2,vt3);
    }
  }
  float4 qt;
  qt.x=c0*qw[G*16+0] +c1*qw[G*16+1] +c2*qw[G*16+2] +c3*qw[G*16+3];
  qt.y=c0*qw[G*16+4] +c1*qw[G*16+5] +c2*qw[G*16+6] +c3*qw[G*16+7];
  qt.z=c0*qw[G*16+8] +c1*qw[G*16+9] +c2*qw[G*16+10]+c3*qw[G*16+11];
  qt.w=c0*qw[G*16+12]+c1*qw[G*16+13]+c2*qw[G*16+14]+c3*qw[G*16+15];
  grp<G>(q)=qt;
  axpy18(x, skp[C0+0]*c0*s0, dwn+(C0+0)*18);
  axpy18(x, skp[C0+1]*c1*s1, dwn+(C0+1)*18);
  axpy18(x, skp[C0+2]*c2*s2, dwn+(C0+2)*18);
  axpy18(x, skp[C0+3]*c3*s3, dwn+(C0+3)*18);
}

#define UNP(u, lo, hi) const float lo = u2f((u)<<16); const float hi = u2f((u)&0xffff0000u);

// one attention head: QK+D+PV pass over LDS rows, then norm + LN + fold into x
template<int HH>
__device__ __forceinline__ void attn_fold(const V36& q, V18& x, int lane,
    const float* KV, const unsigned short* szrow,
    float ipt, float lf, float u,
    const float* __restrict__ onw, const float* __restrict__ dwn)
{
  V18 acc;
  { float4 z4{0.f,0.f,0.f,0.f}; acc.a=z4; acc.b=z4; acc.c=z4; acc.d=z4; acc.e.x=0.f; acc.e.y=0.f; }
  float rs=0.f;
  const float rb=-u;
  const float scl=0.23570226039551584f;
  for(int t=0;t<48;++t){
    const float ipx = __shfl(ipt, t);
    const float* r = KV + t*56;
    float qk;
    if constexpr(HH==0){
      const float4 k0=*reinterpret_cast<const float4*>(r);
      const float4 k1=*reinterpret_cast<const float4*>(r+4);
      const float4 k2=*reinterpret_cast<const float4*>(r+8);
      const float4 k3=*reinterpret_cast<const float4*>(r+12);
      const float2 k4=*reinterpret_cast<const float2*>(r+16);
      qk = dot4(k0,q.g0)+dot4(k1,q.g1)+dot4(k2,q.g2)+dot4(k3,q.g3)
         + k4.x*q.g4.x + k4.y*q.g4.y;
    } else {
      const float2 k0=*reinterpret_cast<const float2*>(r+18);
      const float2 k1=*reinterpret_cast<const float2*>(r+20);
      const float2 k2=*reinterpret_cast<const float2*>(r+22);
      const float2 k3=*reinterpret_cast<const float2*>(r+24);
      const float2 k4=*reinterpret_cast<const float2*>(r+26);
      const float2 k5=*reinterpret_cast<const float2*>(r+28);
      const float2 k6=*reinterpret_cast<const float2*>(r+30);
      const float2 k7=*reinterpret_cast<const float2*>(r+32);
      const float2 k8=*reinterpret_cast<const float2*>(r+34);
      qk = k0.x*q.g4.z + k0.y*q.g4.w
         + k1.x*q.g5.x + k1.y*q.g5.y + k2.x*q.g5.z + k2.y*q.g5.w
         + k3.x*q.g6.x + k3.y*q.g6.y + k4.x*q.g6.z + k4.y*q.g6.w
         + k5.x*q.g7.x + k5.y*q.g7.y + k6.x*q.g7.z + k6.y*q.g7.w
         + k7.x*q.g8.x + k7.y*q.g8.y + k8.x*q.g8.z + k8.y*q.g8.w;
    }
    const float e0=__expf(fminf(rb+ipx,0.f));
    const float cc = (t<=lane)? qk*scl*e0 : 0.f;
    rs+=cc;
    const unsigned* ur = reinterpret_cast<const unsigned*>(r);
    if constexpr(HH==0){
      const uint4 va=*reinterpret_cast<const uint4*>(ur+36);
      const uint4 vb=*reinterpret_cast<const uint4*>(ur+40);
      const unsigned vc=ur[44];
      UNP(va.x,v0,v1) UNP(va.y,v2,v3) UNP(va.z,v4,v5) UNP(va.w,v6,v7)
      UNP(vb.x,v8,v9) UNP(vb.y,v10,v11) UNP(vb.z,v12,v13) UNP(vb.w,v14,v15)
      UNP(vc,v16,v17)
      acc.a.x+=cc*v0;  acc.a.y+=cc*v1;  acc.a.z+=cc*v2;  acc.a.w+=cc*v3;
      acc.b.x+=cc*v4;  acc.b.y+=cc*v5;  acc.b.z+=cc*v6;  acc.b.w+=cc*v7;
      acc.c.x+=cc*v8;  acc.c.y+=cc*v9;  acc.c.z+=cc*v10; acc.c.w+=cc*v11;
      acc.d.x+=cc*v12; acc.d.y+=cc*v13; acc.d.z+=cc*v14; acc.d.w+=cc*v15;
      acc.e.x+=cc*v16; acc.e.y+=cc*v17;
    } else {
      const uint2 w0=*reinterpret_cast<const uint2*>(ur+46);
      const uint4 w1=*reinterpret_cast<const uint4*>(ur+48);
      const uint2 w2=*reinterpret_cast<const uint2*>(ur+52);
      const unsigned w3=ur[54];
      UNP(w0.x,v0,v1) UNP(w0.y,v2,v3) UNP(w1.x,v4,v5) UNP(w1.y,v6,v7)
      UNP(w1.z,v8,v9) UNP(w1.w,v10,v11) UNP(w2.x,v12,v13) UNP(w2.y,v14,v15)
      UNP(w3,v16,v17)
      acc.a.x+=cc*v0;  acc.a.y+=cc*v1;  acc.a.z+=cc*v2;  acc.a.w+=cc*v3;
      acc.b.x+=cc*v4;  acc.b.y+=cc*v5;  acc.b.z+=cc*v6;  acc.b.w+=cc*v7;
      acc.c.x+=cc*v8;  acc.c.y+=cc*v9;  acc.c.z+=cc*v10; acc.c.w+=cc*v11;
      acc.d.x+=cc*v12; acc.d.y+=cc*v13; acc.d.z+=cc*v14; acc.d.w+=cc*v15;
      acc.e.x+=cc*v16; acc.e.y+=cc*v17;
    }
  }
  const float mr = lf+u;
  const float ninv = 1.f/(fmaxf(fabsf(rs), __expf(-mr))+1e-6f);
  #define AS(I) + elc<I>(acc)
  const float mb = (0.f L18(AS))*(1.f/18.f);
  #undef AS
  #define AV(I) + sqf(elc<I>(acc)-mb)
  const float vb2 = 0.f L18(AV);
  #undef AV
  const float rn = rsqrtf(ninv*ninv*vb2*(1.f/18.f)+1e-5f);
  #define FD(I) { const float hn=(elc<I>(acc)-mb)*ninv*rn*onw[HH*18+I]; \
                  axpy18(x, hn*b2f(szrow[HH*18+I]), dwn+(HH*18+I)*18); }
  L18(FD)
  #undef FD
}

__device__ __forceinline__ void mlstm(V18& x, int lane, float* WV, unsigned short* SZB,
    const float* __restrict__ lnw, const float* __restrict__ wup, const float* __restrict__ wab,
    const float* __restrict__ cw,  const float* __restrict__ cb,
    const float* __restrict__ qw,  const float* __restrict__ kw,  const float* __restrict__ vw,
    const float* __restrict__ igb, const float* __restrict__ fgb, const float* __restrict__ skp,
    const float* __restrict__ onw, const float* __restrict__ dwn)
{
  #define MS(I) + elc<I>(x)
  const float mu = (0.f L18(MS))*(1.f/18.f);
  #undef MS
  #define MV(I) + sqf(elc<I>(x)-mu)
  const float var = (0.f L18(MV))*(1.f/18.f);
  #undef MV
  const float rr = rsqrtf(var+1e-5f);
  V18 h;
  #define MH(I) setv<I>(h,(elc<I>(x)-mu)*rr*lnw[I]);
  L18(MH)
  #undef MH

  V36 q;
  float gi0=igb[0], gi1=igb[1], gf0=fgb[0], gf1=fgb[1];
  float* kvrow = WV + lane*56;
  const int sr = (lane<48)? lane : 0;
  unsigned short* szrow = SZB + sr*36;
  proj_g<0>(h,x,q,kvrow,szrow,lane,wup,wab,cw,cb,qw,kw,vw,skp,dwn,gi0,gi1,gf0,gf1);
  proj_g<1>(h,x,q,kvrow,szrow,lane,wup,wab,cw,cb,qw,kw,vw,skp,dwn,gi0,gi1,gf0,gf1);
  proj_g<2>(h,x,q,kvrow,szrow,lane,wup,wab,cw,cb,qw,kw,vw,skp,dwn,gi0,gi1,gf0,gf1);
  proj_g<3>(h,x,q,kvrow,szrow,lane,wup,wab,cw,cb,qw,kw,vw,skp,dwn,gi0,gi1,gf0,gf1);
  proj_g<4>(h,x,q,kvrow,szrow,lane,wup,wab,cw,cb,qw,kw,vw,skp,dwn,gi0,gi1,gf0,gf1);
  proj_g<5>(h,x,q,kvrow,szrow,lane,wup,wab,cw,cb,qw,kw,vw,skp,dwn,gi0,gi1,gf0,gf1);
  proj_g<6>(h,x,q,kvrow,szrow,lane,wup,wab,cw,cb,qw,kw,vw,skp,dwn,gi0,gi1,gf0,gf1);
  proj_g<7>(h,x,q,kvrow,szrow,lane,wup,wab,cw,cb,qw,kw,vw,skp,dwn,gi0,gi1,gf0,gf1);
  proj_g<8>(h,x,q,kvrow,szrow,lane,wup,wab,cw,cb,qw,kw,vw,skp,dwn,gi0,gi1,gf0,gf1);

  float lf0=logsig(gf0), lf1=logsig(gf1);
  #pragma unroll
  for(int off=1; off<64; off<<=1){
    float t0=__shfl_up(lf0,off), t1=__shfl_up(lf1,off);
    if(lane>=off){ lf0+=t0; lf1+=t1; }
  }
  const float ipt0=gi0-lf0, ipt1=gi1-lf1;
  float u0=ipt0, u1=ipt1;
  #pragma unroll
  for(int off=1; off<64; off<<=1){
    float t0=__shfl_up(u0,off), t1=__shfl_up(u1,off);
    if(lane>=off){ u0=fmaxf(u0,t0); u1=fmaxf(u1,t1); }
  }
  asm volatile("s_waitcnt lgkmcnt(0)" ::: "memory");

  attn_fold<0>(q, x, lane, WV, szrow, ipt0, lf0, u0, onw, dwn);
  attn_fold<1>(q, x, lane, WV, szrow, ipt1, lf1, u1, onw, dwn);
}

template<int IDX> __device__ __forceinline__ float wx1(const V18& h, const V18& hc,
    const float* __restrict__ gw, const float* __restrict__ gb){
  constexpr int g=IDX/18, hh=(IDX%18)/9;
  constexpr int B=hh*9;
  const float* w = gw + IDX*9;
  float a = gb[IDX];
  if constexpr(g<2) a += dot9<B>(hc,w); else a += dot9<B>(h,w);
  return a;
}
template<int Q4> __device__ __forceinline__ void wx4(const V18& h, const V18& hc,
    const float* __restrict__ gw, const float* __restrict__ gb, float* kvrow, int lane){
  float4 t;
  t.x=wx1<4*Q4+0>(h,hc,gw,gb);
  t.y=wx1<4*Q4+1>(h,hc,gw,gb);
  t.z=wx1<4*Q4+2>(h,hc,gw,gb);
  t.w=wx1<4*Q4+3>(h,hc,gw,gb);
  if(lane<48) *reinterpret_cast<float4*>(kvrow+4*Q4)=t;
}

__device__ __forceinline__ void slstm(V18& x, int lane, float* KV,
    const float* __restrict__ lnw, const float* __restrict__ cw, const float* __restrict__ cb,
    const float* __restrict__ gw,  const float* __restrict__ rw, const float* __restrict__ gb,
    const float* __restrict__ gnw, const float* __restrict__ flnw,
    const float* __restrict__ wfup,const float* __restrict__ fdw)
{
  #define SS(I) + elc<I>(x)
  const float mu = (0.f L18(SS))*(1.f/18.f);
  #undef SS
  #define SV(I) + sqf(elc<I>(x)-mu)
  const float var = (0.f L18(SV))*(1.f/18.f);
  #undef SV
  const float rr = rsqrtf(var+1e-5f);
  V18 h;
  #define SH(I) setv<I>(h,(lane<48)?(elc<I>(x)-mu)*rr*lnw[I]:0.f);
  L18(SH)
  #undef SH
  V18 hc;
  #define SC(I) { const float hv=elc<I>(h); \
    const float p1=__shfl(hv,lane-1),p2=__shfl(hv,lane-2),p3=__shfl(hv,lane-3); \
    setv<I>(hc, siluf(cb[I]+p3*cw[(I)*4]+p2*cw[(I)*4+1]+p1*cw[(I)*4+2]+hv*cw[(I)*4+3])); }
  L18(SC)
  #undef SC

  float* kvrow = KV + lane*72;   // wx[48][72] overlays the wave buffer (3456 <= 3552)
  wx4<0>(h,hc,gw,gb,kvrow,lane);  wx4<1>(h,hc,gw,gb,kvrow,lane);
  wx4<2>(h,hc,gw,gb,kvrow,lane);  wx4<3>(h,hc,gw,gb,kvrow,lane);
  wx4<4>(h,hc,gw,gb,kvrow,lane);  wx4<5>(h,hc,gw,gb,kvrow,lane);
  wx4<6>(h,hc,gw,gb,kvrow,lane);  wx4<7>(h,hc,gw,gb,kvrow,lane);
  wx4<8>(h,hc,gw,gb,kvrow,lane);  wx4<9>(h,hc,gw,gb,kvrow,lane);
  wx4<10>(h,hc,gw,gb,kvrow,lane); wx4<11>(h,hc,gw,gb,kvrow,lane);
  wx4<12>(h,hc,gw,gb,kvrow,lane); wx4<13>(h,hc,gw,gb,kvrow,lane);
  wx4<14>(h,hc,gw,gb,kvrow,lane); wx4<15>(h,hc,gw,gb,kvrow,lane);
  wx4<16>(h,hc,gw,gb,kvrow,lane); wx4<17>(h,hc,gw,gb,kvrow,lane);
  asm volatile("s_waitcnt lgkmcnt(0)" ::: "memory");

  for(int hh=0;hh<2;++hh){
    const int li = (lane<36)? lane : 0;
    const int g=li/9, e=li%9;
    const float* rwb = rw + hh*324 + g*9 + e;
    const float r0=rwb[0], r1=rwb[36], r2=rwb[72], r3=rwb[108], r4=rwb[144],
                r5=rwb[180], r6=rwb[216], r7=rwb[252], r8=rwb[288];
    float yv=0.f,cv=0.f,nv=0.f,mv=0.f;
    for(int st=0;st<48;++st){
      float raw = KV[st*72 + g*18 + hh*9 + e];
      raw += __shfl(yv,0)*r0 + __shfl(yv,1)*r1 + __shfl(yv,2)*r2
           + __shfl(yv,3)*r3 + __shfl(yv,4)*r4 + __shfl(yv,5)*r5
           + __shfl(yv,6)*r6 + __shfl(yv,7)*r7 + __shfl(yv,8)*r8;
      const float i_=__shfl(raw,e), f_=__shfl(raw,9+e), z_=__shfl(raw,18+e), o_=__shfl(raw,27+e);
      const float lfm=mv+logsig(f_);
      const float mn=fmaxf(i_,lfm);
      const float ig=__expf(i_-mn), fg=__expf(lfm-mn);
      const float th=1.f-2.f/(__expf(2.f*z_)+1.f);
      cv=fg*cv+ig*th;
      nv=fg*nv+ig; mv=mn;
      yv=sigm(o_)*cv/nv;
      if(lane<9) KV[st*72+hh*9+lane]=yv;
    }
  }
  asm volatile("s_waitcnt lgkmcnt(0)" ::: "memory");

  if(lane<48){
    {
      float m2=0.f;
      for(int e=0;e<9;++e) m2+=KV[lane*72+e];
      m2*=(1.f/9.f);
      float vv=0.f;
      for(int e=0;e<9;++e){ float t=KV[lane*72+e]-m2; vv+=t*t; }
      const float r2=rsqrtf(vv*(1.f/9.f)+1e-5f);
      #define GN0(E) setv<E>(x, elc<E>(x)+(KV[lane*72+E]-m2)*r2*gnw[E]);
      L9(GN0)
      #undef GN0
    }
    {
      float m2=0.f;
      for(int e=0;e<9;++e) m2+=KV[lane*72+9+e];
      m2*=(1.f/9.f);
      float vv=0.f;
      for(int e=0;e<9;++e){ float t=KV[lane*72+9+e]-m2; vv+=t*t; }
      const float r2=rsqrtf(vv*(1.f/9.f)+1e-5f);
      #define GN1(E) setv<(9+E)>(x, elc<(9+E)>(x)+(KV[lane*72+9+E]-m2)*r2*gnw[9+E]);
      L9(GN1)
      #undef GN1
    }
  }

  #define FS(I) + elc<I>(x)
  const float mu2 = (0.f L18(FS))*(1.f/18.f);
  #undef FS
  #define FV(I) + sqf(elc<I>(x)-mu2)
  const float var2 = (0.f L18(FV))*(1.f/18.f);
  #undef FV
  const float rr2 = rsqrtf(var2+1e-5f);
  V18 h2;
  #define FH(I) setv<I>(h2,(elc<I>(x)-mu2)*rr2*flnw[I]);
  L18(FH)
  #undef FH
  for(int f=0;f<64;++f){
    const float ug=dot18(h2, wfup+f*18);
    const float uu=dot18(h2, wfup+(64+f)*18);
    const float ge=0.5f*ug*(1.f+erff(ug*0.70710678118654752f));
    axpy18(x, ge*uu, fdw+f*18);
  }
}

extern "C" __global__ void __launch_bounds__(TPB)
xlstm_kernel(const float* __restrict__ gx,
             const float* __restrict__ m_ln_w,  const float* __restrict__ m_conv_w,
             const float* __restrict__ m_conv_b,const float* __restrict__ m_q_w,
             const float* __restrict__ m_k_w,   const float* __restrict__ m_v_w,
             const float* __restrict__ m_ig_b,  const float* __restrict__ m_fg_b,
             const float* __restrict__ m_skip,  const float* __restrict__ m_on_w,
             const float* __restrict__ m_down_w,
             const float* __restrict__ s_ln_w,  const float* __restrict__ s_conv_w,
             const float* __restrict__ s_conv_b,const float* __restrict__ s_gate_w,
             const float* __restrict__ s_rec_w, const float* __restrict__ s_bias,
             const float* __restrict__ s_gn_w,  const float* __restrict__ f_ln_w,
             const float* __restrict__ f_down_w,
             const float* __restrict__ post_ln_w, const float* __restrict__ dense_w,
             const float* __restrict__ dense_b, const float* __restrict__ W,
             float* __restrict__ gout, const int Btot)
{
  __shared__ float L[WPB*WAVE_F];
  const int lane = threadIdx.x & 63;
  const int wv   = threadIdx.x >> 6;
  const int b    = blockIdx.x*WPB + wv;
  if (b >= Btot) return;
  float* WV = L + wv*WAVE_F;
  unsigned short* SZB = reinterpret_cast<unsigned short*>(WV + O_SZ);

  V18 x;
  const float* gxb = gx + b*864 + lane*18;
  #define XL(I) setv<I>(x,(lane<48)? gxb[I] : 0.f);
  L18(XL)
  #undef XL

  int mj=0;
  #pragma unroll 1
  for(int blk=0; blk<7; ++blk){
    if (blk==1){
      slstm(x, lane, WV, s_ln_w, s_conv_w, s_conv_b, s_gate_w, s_rec_w, s_bias,
            s_gn_w, f_ln_w, W+OW_FUP, f_down_w);
    } else {
      mlstm(x, lane, WV, SZB,
            m_ln_w+mj*18, W+OW_UP+mj*1296, W+OW_AB+mj*288,
            m_conv_w+mj*144, m_conv_b+mj*36,
            m_q_w+mj*144, m_k_w+mj*144, m_v_w+mj*144,
            m_ig_b+mj*2, m_fg_b+mj*2, m_skip+mj*36, m_on_w+mj*36,
            m_down_w+mj*648);
      ++mj;
    }
  }

  if (lane<48){
    #define OS(I) + elc<I>(x)
    const float mu = (0.f L18(OS))*(1.f/18.f);
    #undef OS
    #define OV(I) + sqf(elc<I>(x)-mu)
    const float var = (0.f L18(OV))*(1.f/18.f);
    #undef OV
    const float rr = rsqrtf(var+1e-5f);
    float acc = dense_b[0];
    #define OD(I) acc += (elc<I>(x)-mu)*rr*post_ln_w[I]*dense_w[I];
    L18(OD)
    #undef OD
    gout[b*48+lane] = (lane<24) ? 0.f : acc;
  }
}

extern "C" void kernel_launch(void* const* d_in, const int* in_sizes, int n_in,
                              void* d_out, int out_size, void* d_ws, size_t ws_size,
                              hipStream_t stream)
{
  const float* gx        = (const float*)d_in[0];
  const float* m_ln_w    = (const float*)d_in[1];
  const float* m_up_w    = (const float*)d_in[2];
  const float* m_conv_w  = (const float*)d_in[3];
  const float* m_conv_b  = (const float*)d_in[4];
  const float* m_q_w     = (const float*)d_in[5];
  const float* m_k_w     = (const float*)d_in[6];
  const float* m_v_w     = (const float*)d_in[7];
  const float* m_ig_w    = (const float*)d_in[8];
  const float* m_ig_b    = (const float*)d_in[9];
  const float* m_fg_w    = (const float*)d_in[10];
  const float* m_fg_b    = (const float*)d_in[11];
  const float* m_skip    = (const float*)d_in[12];
  const float* m_on_w    = (const float*)d_in[13];
  const float* m_down_w  = (const float*)d_in[14];
  const float* s_ln_w    = (const float*)d_in[15];
  const float* s_conv_w  = (const float*)d_in[16];
  const float* s_conv_b  = (const float*)d_in[17];
  const float* s_gate_w  = (const float*)d_in[18];
  const float* s_rec_w   = (const float*)d_in[19];
  const float* s_bias    = (const float*)d_in[20];
  const float* s_gn_w    = (const float*)d_in[21];
  const float* f_ln_w    = (const float*)d_in[22];
  const float* f_up_w    = (const float*)d_in[23];
  const float* f_down_w  = (const float*)d_in[24];
  const float* post_ln_w = (const float*)d_in[25];
  const float* dense_w   = (const float*)d_in[26];
  const float* dense_b   = (const float*)d_in[27];

  float* W = (float*)d_ws;
  const int B = in_sizes[0] / (48*18);

  prep_kernel<<<1, 256, 0, stream>>>(m_up_w, m_q_w, m_k_w, m_v_w, m_ig_w, m_fg_w,
                                     f_up_w, W);
  xlstm_kernel<<<(B+WPB-1)/WPB, TPB, 0, stream>>>(gx,
    m_ln_w, m_conv_w, m_conv_b, m_q_w, m_k_w, m_v_w,
    m_ig_b, m_fg_b, m_skip, m_on_w, m_down_w,
    s_ln_w, s_conv_w, s_conv_b, s_gate_w, s_rec_w, s_bias, s_gn_w,
    f_ln_w, f_down_w, post_ln_w, dense_w, dense_b, W, (float*)d_out, B);
}